// Round 8
// baseline (1144.750 us; speedup 1.0000x reference)
//
#include <hip/hip_runtime.h>
#include <cstddef>

// ---------------------------------------------------------------------------
// GAT 3-layer pipeline, round 16.
// R16: pipeline compaction — 15 dispatches -> 10.
//  - amax kernels DELETED: producers (split_att / agg01 fused-dots epilogue)
//    fold a block-level max + 4 order-preserving atomicMax into their
//    epilogues. max is order-independent -> identical amax values.
//  - degree merged into wprep (independent work, concatenated grid).
//  - scatter merged into split_att kernel (both depend only on scan).
// - GEMM (R15): A+B both LDS double-buffered (m97 structure), (256,2).
// - agg01 (R12/R14): two nodes/wave, ushort8 rows, x4 edge batch, (256,6).
// Packed layout (per matrix, rows padded to 128): group g=row>>4, chunk
// c=k>>5, lane l=(row&15)+16*((k&31)>>3), sub=k&7:
//   offset = (g*8+c)*512 + l*8 + sub   (ushorts)
// ---------------------------------------------------------------------------

typedef __bf16 bf16x8 __attribute__((ext_vector_type(8)));
typedef float floatx4 __attribute__((ext_vector_type(4)));
typedef unsigned short ushortx8 __attribute__((ext_vector_type(8)));

__device__ __forceinline__ unsigned short bf16_rn(float f) {
    unsigned int u = __float_as_uint(f);
    u += 0x7FFF + ((u >> 16) & 1);
    return (unsigned short)(u >> 16);
}
__device__ __forceinline__ float bf16_tof(unsigned short h) {
    return __uint_as_float(((unsigned int)h) << 16);
}

__device__ __forceinline__ unsigned int amax_encode(float v) {
    unsigned int u = __float_as_uint(v);
    return (u >> 31) ? ~u : (u | 0x80000000u);
}
__device__ __forceinline__ float amax_decode(unsigned int u) {
    unsigned int bits = (u >> 31) ? (u & 0x7FFFFFFFu) : ~u;
    return __uint_as_float(bits);
}

// 16B-per-lane direct global->LDS copy: lds dest = base + lane*16 (HW rule).
__device__ __forceinline__ void gload_lds16(const void* g, void* l) {
    __builtin_amdgcn_global_load_lds(
        (const __attribute__((address_space(1))) unsigned int*)g,
        (__attribute__((address_space(3))) unsigned int*)l, 16, 0, 0);
}

// ---------------- CSR scan (single block) ----------------

__global__ __launch_bounds__(1024) void scan_kernel(const int* __restrict__ deg,
                                                    int* __restrict__ off, int n) {
    __shared__ int wsum[16];
    __shared__ int carry_s;
    int tid = threadIdx.x, lane = tid & 63, wid = tid >> 6;
    if (tid == 0) { carry_s = 0; off[0] = 0; }
    __syncthreads();
    for (int base = 0; base < n; base += 1024) {
        int i = base + tid;
        int v = (i < n) ? deg[i] : 0;
        int s = v;
        #pragma unroll
        for (int d = 1; d < 64; d <<= 1) {
            int t = __shfl_up(s, d, 64);
            if (lane >= d) s += t;
        }
        if (lane == 63) wsum[wid] = s;
        __syncthreads();
        if (wid == 0) {
            int wv = (lane < 16) ? wsum[lane] : 0;
            #pragma unroll
            for (int d = 1; d < 16; d <<= 1) {
                int t = __shfl_up(wv, d, 64);
                if (lane >= d) wv += t;
            }
            if (lane < 16) wsum[lane] = wv;
        }
        __syncthreads();
        int prev = (wid > 0) ? wsum[wid - 1] : 0;
        int inc = carry_s + prev + s;
        if (i < n) off[i + 1] = inc;
        int chunk_total = wsum[15];
        __syncthreads();
        if (tid == 0) carry_s += chunk_total;
        __syncthreads();
    }
}

// ---------------- merged: weight prep + att folds + degree count -------------

__global__ __launch_bounds__(256) void wprep_kernel(
    const float* __restrict__ W0, const float* __restrict__ lw0,
    const float* __restrict__ W1, const float* __restrict__ lw1,
    const float* __restrict__ W2, const float* __restrict__ lw2,
    ushort* __restrict__ B0h, ushort* __restrict__ B0l,
    ushort* __restrict__ B1h, ushort* __restrict__ B1l,
    ushort* __restrict__ B2h, ushort* __restrict__ B2l,
    const float* __restrict__ as0, const float* __restrict__ ad0,
    const float* __restrict__ as1, const float* __restrict__ ad1,
    const float* __restrict__ as2, const float* __restrict__ ad2,
    float* __restrict__ vsd0, float* __restrict__ vsd1, float* __restrict__ vsd2,
    const int* __restrict__ edst, int* __restrict__ deg, int E)
{
    int bid = blockIdx.x, tid = threadIdx.x;
    if (bid < 1664) {
        const float* src; ushort* dh; ushort* dl; int Ncols, roff, base;
        if (bid < 256)       { src = W0;  dh = B0h; dl = B0l; Ncols = 256; roff = 0;   base = 0; }
        else if (bid < 512)  { src = lw0; dh = B0h; dl = B0l; Ncols = 256; roff = 256; base = 256; }
        else if (bid < 768)  { src = W1;  dh = B1h; dl = B1l; Ncols = 256; roff = 0;   base = 512; }
        else if (bid < 1024) { src = lw1; dh = B1h; dl = B1l; Ncols = 256; roff = 256; base = 768; }
        else if (bid < 1536) { src = W2;  dh = B2h; dl = B2l; Ncols = 512; roff = 0;   base = 1024; }
        else                 { src = lw2; dh = B2h; dl = B2l; Ncols = 128; roff = 512; base = 1536; }
        int idx = (bid - base) * 256 + tid;
        int k = idx / Ncols, n = idx - k * Ncols;
        float v = src[idx];
        unsigned short hi = bf16_rn(v);
        unsigned short lo = bf16_rn(v - bf16_tof(hi));
        int row = n + roff;
        int poff = ((row >> 4) * 8 + (k >> 5)) * 512 + (((row & 15) + 16 * ((k & 31) >> 3)) << 3) + (k & 7);
        dh[poff] = hi;
        dl[poff] = lo;
    } else if (bid < 1676) {
        int fj = (bid - 1664) >> 2;
        int idx = ((bid - 1664) & 3) * 256 + tid;   // 0..1023 = K*H
        const float *W, *as_, *ad_; float* vsd; int C;
        if (fj == 0)      { W = W0; as_ = as0; ad_ = ad0; vsd = vsd0; C = 64; }
        else if (fj == 1) { W = W1; as_ = as1; ad_ = ad1; vsd = vsd1; C = 64; }
        else              { W = W2; as_ = as2; ad_ = ad2; vsd = vsd2; C = 128; }
        int k = idx >> 2, hh = idx & 3;
        const float* wp = W + (size_t)k * (4 * C) + hh * C;
        float s = 0.f, d = 0.f;
        for (int c = 0; c < C; c++) {
            float w = wp[c];
            s += w * as_[hh * C + c];
            d += w * ad_[hh * C + c];
        }
        vsd[k * 8 + hh] = s;       // vsd layout: [k][8] = 4 src then 4 dst
        vsd[k * 8 + 4 + hh] = d;
    } else {
        int e = (bid - 1676) * 256 + tid;
        if (e < E) atomicAdd(&deg[edst[e]], 1);
    }
}

// ---------------- merged: scatter + (x -> packed + layer-0 dots + amax) ------
// Blocks [0, egrid): CSR scatter. Blocks [egrid, ...): split_att, two nodes
// per wave, with fused per-block amax reduction + atomicMax.

__global__ __launch_bounds__(256, 6) void scatter_split_kernel(
    const int* __restrict__ esrc, const int* __restrict__ edst,
    const int* __restrict__ off, int* __restrict__ cursor,
    int* __restrict__ csrc, int E, int egrid,
    const float* __restrict__ x, const float* __restrict__ vsd,
    ushort* __restrict__ Aph, ushort* __restrict__ Apl,
    float* __restrict__ asrc, float* __restrict__ adst,
    unsigned int* __restrict__ amax, int n)
{
    int bid = blockIdx.x;
    if (bid < egrid) {
        int e = bid * 256 + threadIdx.x;
        if (e < E) {
            int d = edst[e];
            int p = off[d] + atomicAdd(&cursor[d], 1);
            csrc[p] = esrc[e];
        }
        return;
    }
    int sb = bid - egrid;
    int wid = threadIdx.x >> 6, lane = threadIdx.x & 63;
    int half = lane >> 5, sl = lane & 31;
    int d = sb * 8 + wid * 2 + half;
    bool valid = (d < n);
    int dd = valid ? d : (n - 1);

    __shared__ float smx[8][4];
    if (threadIdx.x < 32) ((float*)smx)[threadIdx.x] = -1e30f;
    __syncthreads();

    int k0 = sl * 8;
    float4 va = *(const float4*)(x + (size_t)dd * 256 + k0);
    float4 vb = *(const float4*)(x + (size_t)dd * 256 + k0 + 4);
    float v[8] = {va.x, va.y, va.z, va.w, vb.x, vb.y, vb.z, vb.w};

    if (valid) {
        ushortx8 hi, lo;
        #pragma unroll
        for (int j = 0; j < 8; ++j) {
            unsigned short h8 = bf16_rn(v[j]);
            hi[j] = h8;
            lo[j] = bf16_rn(v[j] - bf16_tof(h8));
        }
        int poff = ((dd >> 4) * 8 + (k0 >> 5)) * 512 + (((dd & 15) + 16 * ((k0 & 31) >> 3)) << 3);
        *(ushortx8*)(Aph + poff) = hi;
        *(ushortx8*)(Apl + poff) = lo;
    }

    // attention dots: pa/pb[h] = sum_k v[k] * vsd[k][h] (+4 for dst)
    const float* vp = vsd + (size_t)k0 * 8;
    float pa[4] = {0.f, 0.f, 0.f, 0.f}, pb[4] = {0.f, 0.f, 0.f, 0.f};
    #pragma unroll
    for (int r = 0; r < 8; ++r) {
        float4 ra = *(const float4*)(vp + r * 8);
        float4 rb = *(const float4*)(vp + r * 8 + 4);
        pa[0] += v[r] * ra.x; pa[1] += v[r] * ra.y;
        pa[2] += v[r] * ra.z; pa[3] += v[r] * ra.w;
        pb[0] += v[r] * rb.x; pb[1] += v[r] * rb.y;
        pb[2] += v[r] * rb.z; pb[3] += v[r] * rb.w;
    }
    #pragma unroll
    for (int o = 1; o < 32; o <<= 1) {
        #pragma unroll
        for (int j = 0; j < 4; ++j) {
            pa[j] += __shfl_xor(pa[j], o, 64);
            pb[j] += __shfl_xor(pb[j], o, 64);
        }
    }
    if (valid && sl == 0) {
        *(float4*)(asrc + (size_t)dd * 4) = make_float4(pa[0], pa[1], pa[2], pa[3]);
        *(float4*)(adst + (size_t)dd * 4) = make_float4(pb[0], pb[1], pb[2], pb[3]);
        #pragma unroll
        for (int j = 0; j < 4; ++j) smx[wid * 2 + half][j] = pa[j];
    }
    __syncthreads();
    if (threadIdx.x < 4) {
        float m = smx[0][threadIdx.x];
        #pragma unroll
        for (int s = 1; s < 8; ++s) m = fmaxf(m, smx[s][threadIdx.x]);
        atomicMax(&amax[threadIdx.x], amax_encode(m));
    }
}

// ---------------- LDS MFMA GEMM on packed operands (m97 structure) -----------
// BM=BN=128, 4 waves (64x64 each), K=256 in 8 chunks of 32.
// Per chunk 32KB LDS: [A-hi 8K | A-lo 8K | B-hi 8K | B-lo 8K], double-buffered
// (64KB). Wave w stages region w: 8 x 1KB gload_lds16 per chunk.

__global__ __launch_bounds__(256, 2) void gemm_mfma_kernel(
    const ushort* __restrict__ Aph, const ushort* __restrict__ Apl,
    const ushort* __restrict__ Bph, const ushort* __restrict__ Bpl,
    ushort* __restrict__ O1, int n1, ushort* __restrict__ O2,
    const float* __restrict__ bias2,
    int gm, int M, int N)
{
    __shared__ __align__(16) char smem[65536];   // 2 buffers x 32KB
    int gy = N >> 7;
    int bid = blockIdx.x;
    int k8 = bid & 7, sb = bid >> 3;
    int ny = sb % gy, bxi = sb / gy;
    int bx = bxi * 8 + k8;
    if (bx >= gm) return;
    int bm = bx * 128, bn = ny * 128;

    int tid = threadIdx.x, lane = tid & 63, wv = tid >> 6;
    int wm = (wv >> 1) * 64, wn = (wv & 1) * 64;
    int fr = lane & 15, q = lane >> 4;

    // staging role: wave 0 -> A-hi, 1 -> A-lo, 2 -> B-hi, 3 -> B-lo
    const ushort* sp;
    size_t gbase;
    if (wv == 0)      { sp = Aph; gbase = (size_t)(bm >> 4) * 4096; }
    else if (wv == 1) { sp = Apl; gbase = (size_t)(bm >> 4) * 4096; }
    else if (wv == 2) { sp = Bph; gbase = (size_t)(bn >> 4) * 4096; }
    else              { sp = Bpl; gbase = (size_t)(bn >> 4) * 4096; }
    size_t gsrc = gbase + (size_t)lane * 8;   // ushort offset; 16B per lane
    int lbase = wv * 8192;                    // byte offset of this wave's region

    int agl = (wv >> 1) * 4;   // A group base for reads (= wm/16)
    int bgl = (wv & 1) * 4;    // B group base for reads (= wn/16)

    floatx4 acc[4][4] = {};

    // prologue: stage chunk 0 into buffer 0 (8 x 1KB per wave)
    #pragma unroll
    for (int t = 0; t < 8; ++t)
        gload_lds16(sp + gsrc + (size_t)t * 4096, smem + lbase + t * 1024);
    __syncthreads();

    #pragma unroll
    for (int it = 0; it < 8; ++it) {
        int cur = (it & 1) << 15;   // 0 / 32768
        if (it < 7) {
            int nb = ((it + 1) & 1) << 15;
            size_t co = gsrc + (size_t)(it + 1) * 512;
            #pragma unroll
            for (int t = 0; t < 8; ++t)
                gload_lds16(sp + co + (size_t)t * 4096, smem + nb + lbase + t * 1024);
        }
        bf16x8 cah[4], cal[4], cbh[4], cbl[4];
        #pragma unroll
        for (int i = 0; i < 4; ++i) {
            cah[i] = *(const bf16x8*)(smem + cur + (agl + i) * 1024 + lane * 16);
            cal[i] = *(const bf16x8*)(smem + cur + 8192 + (agl + i) * 1024 + lane * 16);
            cbh[i] = *(const bf16x8*)(smem + cur + 16384 + (bgl + i) * 1024 + lane * 16);
            cbl[i] = *(const bf16x8*)(smem + cur + 24576 + (bgl + i) * 1024 + lane * 16);
        }
        #pragma unroll
        for (int i = 0; i < 4; ++i)
            #pragma unroll
            for (int j = 0; j < 4; ++j) {
                acc[i][j] = __builtin_amdgcn_mfma_f32_16x16x32_bf16(cah[i], cbh[j], acc[i][j], 0, 0, 0);
                acc[i][j] = __builtin_amdgcn_mfma_f32_16x16x32_bf16(cah[i], cbl[j], acc[i][j], 0, 0, 0);
                acc[i][j] = __builtin_amdgcn_mfma_f32_16x16x32_bf16(cal[i], cbh[j], acc[i][j], 0, 0, 0);
            }
        if (it < 7) __syncthreads();
    }

    // ---- C store (C/D layout: col=lane&15, row=(lane>>4)*4+reg) ----
    int n2 = N - n1;
    #pragma unroll
    for (int i = 0; i < 4; ++i) {
        #pragma unroll
        for (int r = 0; r < 4; ++r) {
            int grow = bm + wm + i * 16 + q * 4 + r;
            if (grow < M) {
                #pragma unroll
                for (int j = 0; j < 4; ++j) {
                    int gcol = bn + wn + j * 16 + fr;
                    float v = acc[i][j][r];
                    if (gcol < n1) {
                        O1[(size_t)grow * n1 + gcol] = bf16_rn(v);
                    } else {
                        v += bias2[gcol - n1];
                        O2[(size_t)grow * n2 + (gcol - n1)] = bf16_rn(v);
                    }
                }
            }
        }
    }
}

// ---------------- aggregation layers 0/1: TWO nodes per wave -----------------
// 32 lanes per node, 8 cols/lane (ushort8 16B row loads), x4 edge batch.
// Fused next-layer attention dots + per-block amax_next atomicMax.

__global__ __launch_bounds__(256, 6) void agg01_kernel(
    const ushort* __restrict__ h,    // [N,256] bf16
    const float* __restrict__ asrc, const float* __restrict__ adst,
    const unsigned int* __restrict__ amax,
    const int* __restrict__ off, const int* __restrict__ csrc,
    const ushort* __restrict__ lin,  // [N,256] bf16 (lb applied in GEMM)
    const float* __restrict__ bias,  // [256]
    ushort* __restrict__ Aph, ushort* __restrict__ Apl,   // packed act out
    const float* __restrict__ vsd_next,                   // [256][8]
    float* __restrict__ asrc_out, float* __restrict__ adst_out,
    unsigned int* __restrict__ amax_next,
    int n)
{
    int wid = threadIdx.x >> 6, lane = threadIdx.x & 63;
    int half = lane >> 5, sl = lane & 31;
    int d = blockIdx.x * 8 + wid * 2 + half;
    bool valid = (d < n);
    int dd = valid ? d : (n - 1);
    int head = sl >> 3;          // 8 lanes per head; head = c0>>6
    int c0 = sl * 8;             // 8 cols per lane

    __shared__ float smx[8][4];
    if (threadIdx.x < 32) ((float*)smx)[threadIdx.x] = -1e30f;
    __syncthreads();

    float a_d = adst[dd * 4 + head];
    float mh = amax_decode(amax[head]) + a_d;
    float m = (mh > 0.f) ? mh : 0.2f * mh;   // >= true segment max
    int s0 = off[dd], s1 = valid ? off[dd + 1] : s0;

    float denom = 0.f;
    float ac[8] = {0.f, 0.f, 0.f, 0.f, 0.f, 0.f, 0.f, 0.f};
    int i = s0;
    for (; i + 4 <= s1; i += 4) {
        int sa = csrc[i], sb = csrc[i + 1], sc = csrc[i + 2], sd = csrc[i + 3];
        float ea = asrc[sa * 4 + head];
        float eb = asrc[sb * 4 + head];
        float ec = asrc[sc * 4 + head];
        float ed = asrc[sd * 4 + head];
        ushortx8 hva = *(const ushortx8*)(h + (size_t)sa * 256 + c0);
        ushortx8 hvb = *(const ushortx8*)(h + (size_t)sb * 256 + c0);
        ushortx8 hvc = *(const ushortx8*)(h + (size_t)sc * 256 + c0);
        ushortx8 hvd = *(const ushortx8*)(h + (size_t)sd * 256 + c0);
        ea += a_d; ea = (ea > 0.f) ? ea : 0.2f * ea; float wa = __expf(ea - m);
        eb += a_d; eb = (eb > 0.f) ? eb : 0.2f * eb; float wb = __expf(eb - m);
        ec += a_d; ec = (ec > 0.f) ? ec : 0.2f * ec; float wc = __expf(ec - m);
        ed += a_d; ed = (ed > 0.f) ? ed : 0.2f * ed; float wd = __expf(ed - m);
        denom += wa;
        #pragma unroll
        for (int j = 0; j < 8; ++j) ac[j] += wa * bf16_tof(hva[j]);
        denom += wb;
        #pragma unroll
        for (int j = 0; j < 8; ++j) ac[j] += wb * bf16_tof(hvb[j]);
        denom += wc;
        #pragma unroll
        for (int j = 0; j < 8; ++j) ac[j] += wc * bf16_tof(hvc[j]);
        denom += wd;
        #pragma unroll
        for (int j = 0; j < 8; ++j) ac[j] += wd * bf16_tof(hvd[j]);
    }
    for (; i < s1; ++i) {
        int s = csrc[i];
        float e = asrc[s * 4 + head] + a_d;
        e = (e > 0.f) ? e : 0.2f * e;
        float w = __expf(e - m);
        denom += w;
        ushortx8 hv = *(const ushortx8*)(h + (size_t)s * 256 + c0);
        #pragma unroll
        for (int j = 0; j < 8; ++j) ac[j] += w * bf16_tof(hv[j]);
    }

    if (valid) {
        float inv = 1.f / (denom + 1e-16f);
        float4 b4a = *(const float4*)(bias + c0);
        float4 b4b = *(const float4*)(bias + c0 + 4);
        ushortx8 l8 = *(const ushortx8*)(lin + (size_t)dd * 256 + c0);
        float v[8];
        v[0] = ac[0] * inv + b4a.x + bf16_tof(l8[0]);
        v[1] = ac[1] * inv + b4a.y + bf16_tof(l8[1]);
        v[2] = ac[2] * inv + b4a.z + bf16_tof(l8[2]);
        v[3] = ac[3] * inv + b4a.w + bf16_tof(l8[3]);
        v[4] = ac[4] * inv + b4b.x + bf16_tof(l8[4]);
        v[5] = ac[5] * inv + b4b.y + bf16_tof(l8[5]);
        v[6] = ac[6] * inv + b4b.z + bf16_tof(l8[6]);
        v[7] = ac[7] * inv + b4b.w + bf16_tof(l8[7]);
        #pragma unroll
        for (int j = 0; j < 8; ++j)
            v[j] = (v[j] > 0.f) ? v[j] : (__expf(v[j]) - 1.f);   // ELU

        // packed act write (8 consecutive k in one 16B store)
        ushortx8 oh, ol;
        #pragma unroll
        for (int j = 0; j < 8; ++j) {
            unsigned short hi = bf16_rn(v[j]);
            oh[j] = hi;
            ol[j] = bf16_rn(v[j] - bf16_tof(hi));
        }
        int poff = ((dd >> 4) * 8 + (c0 >> 5)) * 512 + (((dd & 15) + 16 * ((c0 & 31) >> 3)) << 3);
        *(ushortx8*)(Aph + poff) = oh;
        *(ushortx8*)(Apl + poff) = ol;

        // fused next-layer attention dots (act-derived, exact fp32 values)
        const float* vp = vsd_next + (size_t)c0 * 8;
        float pa[4] = {0.f, 0.f, 0.f, 0.f}, pb[4] = {0.f, 0.f, 0.f, 0.f};
        #pragma unroll
        for (int r = 0; r < 8; ++r) {
            float4 ra = *(const float4*)(vp + r * 8);
            float4 rb = *(const float4*)(vp + r * 8 + 4);
            pa[0] += v[r] * ra.x; pa[1] += v[r] * ra.y;
            pa[2] += v[r] * ra.z; pa[3] += v[r] * ra.w;
            pb[0] += v[r] * rb.x; pb[1] += v[r] * rb.y;
            pb[2] += v[r] * rb.z; pb[3] += v[r] * rb.w;
        }
        #pragma unroll
        for (int o = 1; o < 32; o <<= 1) {
            #pragma unroll
            for (int j = 0; j < 4; ++j) {
                pa[j] += __shfl_xor(pa[j], o, 64);
                pb[j] += __shfl_xor(pb[j], o, 64);
            }
        }
        if (sl == 0) {
            *(float4*)(asrc_out + (size_t)dd * 4) = make_float4(pa[0], pa[1], pa[2], pa[3]);
            *(float4*)(adst_out + (size_t)dd * 4) = make_float4(pb[0], pb[1], pb[2], pb[3]);
            #pragma unroll
            for (int j = 0; j < 4; ++j) smx[wid * 2 + half][j] = pa[j];
        }
    }
    __syncthreads();
    if (threadIdx.x < 4) {
        float mx = smx[0][threadIdx.x];
        #pragma unroll
        for (int s = 1; s < 8; ++s) mx = fmaxf(mx, smx[s][threadIdx.x]);
        atomicMax(&amax_next[threadIdx.x], amax_encode(mx));
    }
}

// ---------------- aggregation layer 2: wave-per-node, mean heads -------------
// Edge loop batched x4 (8 row-loads in flight).

__global__ __launch_bounds__(256, 6) void agg2_kernel(
    const ushort* __restrict__ h,    // [N,512] bf16
    const float* __restrict__ asrc, const float* __restrict__ adst,
    const unsigned int* __restrict__ amax,
    const int* __restrict__ off, const int* __restrict__ csrc,
    const ushort* __restrict__ lin,  // [N,128] bf16 (lb2 applied in GEMM)
    const float* __restrict__ bias,  // [128]
    float* __restrict__ out,         // [N,128]
    int n)
{
    int wid = threadIdx.x >> 6, lane = threadIdx.x & 63;
    int d = blockIdx.x * 4 + wid;
    if (d >= n) return;
    int ha = lane >> 5;
    int hb = ha + 2;
    int c0 = lane * 4;
    float ad_a = adst[d * 4 + ha];
    float ad_b = adst[d * 4 + hb];
    float mha = amax_decode(amax[ha]) + ad_a;
    float mhb = amax_decode(amax[hb]) + ad_b;
    float ma = (mha > 0.f) ? mha : 0.2f * mha;
    float mb = (mhb > 0.f) ? mhb : 0.2f * mhb;
    int s0 = off[d], s1 = off[d + 1];

    float da = 0.f, db = 0.f;
    floatx4 aa = {0.f, 0.f, 0.f, 0.f}, ab = {0.f, 0.f, 0.f, 0.f};
    int i = s0;
    for (; i + 4 <= s1; i += 4) {
        int sw = csrc[i], sx = csrc[i + 1], sy = csrc[i + 2], sz = csrc[i + 3];
        float ea0 = asrc[sw * 4 + ha], eb0 = asrc[sw * 4 + hb];
        float ea1 = asrc[sx * 4 + ha], eb1 = asrc[sx * 4 + hb];
        float ea2 = asrc[sy * 4 + ha], eb2 = asrc[sy * 4 + hb];
        float ea3 = asrc[sz * 4 + ha], eb3 = asrc[sz * 4 + hb];
        ushort4 va0 = *(const ushort4*)(h + (size_t)sw * 512 + c0);
        ushort4 vb0 = *(const ushort4*)(h + (size_t)sw * 512 + 256 + c0);
        ushort4 va1 = *(const ushort4*)(h + (size_t)sx * 512 + c0);
        ushort4 vb1 = *(const ushort4*)(h + (size_t)sx * 512 + 256 + c0);
        ushort4 va2 = *(const ushort4*)(h + (size_t)sy * 512 + c0);
        ushort4 vb2 = *(const ushort4*)(h + (size_t)sy * 512 + 256 + c0);
        ushort4 va3 = *(const ushort4*)(h + (size_t)sz * 512 + c0);
        ushort4 vb3 = *(const ushort4*)(h + (size_t)sz * 512 + 256 + c0);
        ea0 += ad_a; ea0 = (ea0 > 0.f) ? ea0 : 0.2f * ea0; float wa0 = __expf(ea0 - ma);
        eb0 += ad_b; eb0 = (eb0 > 0.f) ? eb0 : 0.2f * eb0; float wb0 = __expf(eb0 - mb);
        ea1 += ad_a; ea1 = (ea1 > 0.f) ? ea1 : 0.2f * ea1; float wa1 = __expf(ea1 - ma);
        eb1 += ad_b; eb1 = (eb1 > 0.f) ? eb1 : 0.2f * eb1; float wb1 = __expf(eb1 - mb);
        ea2 += ad_a; ea2 = (ea2 > 0.f) ? ea2 : 0.2f * ea2; float wa2 = __expf(ea2 - ma);
        eb2 += ad_b; eb2 = (eb2 > 0.f) ? eb2 : 0.2f * eb2; float wb2 = __expf(eb2 - mb);
        ea3 += ad_a; ea3 = (ea3 > 0.f) ? ea3 : 0.2f * ea3; float wa3 = __expf(ea3 - ma);
        eb3 += ad_b; eb3 = (eb3 > 0.f) ? eb3 : 0.2f * eb3; float wb3 = __expf(eb3 - mb);
        da += wa0; db += wb0;
        aa[0] += wa0 * bf16_tof(va0.x); aa[1] += wa0 * bf16_tof(va0.y);
        aa[2] += wa0 * bf16_tof(va0.z); aa[3] += wa0 * bf16_tof(va0.w);
        ab[0] += wb0 * bf16_tof(vb0.x); ab[1] += wb0 * bf16_tof(vb0.y);
        ab[2] += wb0 * bf16_tof(vb0.z); ab[3] += wb0 * bf16_tof(vb0.w);
        da += wa1; db += wb1;
        aa[0] += wa1 * bf16_tof(va1.x); aa[1] += wa1 * bf16_tof(va1.y);
        aa[2] += wa1 * bf16_tof(va1.z); aa[3] += wa1 * bf16_tof(va1.w);
        ab[0] += wb1 * bf16_tof(vb1.x); ab[1] += wb1 * bf16_tof(vb1.y);
        ab[2] += wb1 * bf16_tof(vb1.z); ab[3] += wb1 * bf16_tof(vb1.w);
        da += wa2; db += wb2;
        aa[0] += wa2 * bf16_tof(va2.x); aa[1] += wa2 * bf16_tof(va2.y);
        aa[2] += wa2 * bf16_tof(va2.z); aa[3] += wa2 * bf16_tof(va2.w);
        ab[0] += wb2 * bf16_tof(vb2.x); ab[1] += wb2 * bf16_tof(vb2.y);
        ab[2] += wb2 * bf16_tof(vb2.z); ab[3] += wb2 * bf16_tof(vb2.w);
        da += wa3; db += wb3;
        aa[0] += wa3 * bf16_tof(va3.x); aa[1] += wa3 * bf16_tof(va3.y);
        aa[2] += wa3 * bf16_tof(va3.z); aa[3] += wa3 * bf16_tof(va3.w);
        ab[0] += wb3 * bf16_tof(vb3.x); ab[1] += wb3 * bf16_tof(vb3.y);
        ab[2] += wb3 * bf16_tof(vb3.z); ab[3] += wb3 * bf16_tof(vb3.w);
    }
    for (; i < s1; ++i) {
        int s = csrc[i];
        float ea = asrc[s * 4 + ha] + ad_a;
        float eb = asrc[s * 4 + hb] + ad_b;
        ea = (ea > 0.f) ? ea : 0.2f * ea;
        eb = (eb > 0.f) ? eb : 0.2f * eb;
        float wa = __expf(ea - ma), wb = __expf(eb - mb);
        da += wa; db += wb;
        ushort4 va = *(const ushort4*)(h + (size_t)s * 512 + c0);
        ushort4 vb = *(const ushort4*)(h + (size_t)s * 512 + 256 + c0);
        aa[0] += wa * bf16_tof(va.x); aa[1] += wa * bf16_tof(va.y);
        aa[2] += wa * bf16_tof(va.z); aa[3] += wa * bf16_tof(va.w);
        ab[0] += wb * bf16_tof(vb.x); ab[1] += wb * bf16_tof(vb.y);
        ab[2] += wb * bf16_tof(vb.z); ab[3] += wb * bf16_tof(vb.w);
    }
    float ia = 1.f / (da + 1e-16f), ib = 1.f / (db + 1e-16f);
    float s4[4];
    #pragma unroll
    for (int j = 0; j < 4; ++j) s4[j] = aa[j] * ia + ab[j] * ib;
    float p4[4];
    #pragma unroll
    for (int j = 0; j < 4; ++j) p4[j] = __shfl_xor(s4[j], 32, 64);
    if (lane < 32) {
        float4 b4 = *(const float4*)(bias + c0);
        ushort4 l4 = *(const ushort4*)(lin + (size_t)d * 128 + c0);
        float4 o;
        o.x = 0.25f * (s4[0] + p4[0]) + b4.x + bf16_tof(l4.x);
        o.y = 0.25f * (s4[1] + p4[1]) + b4.y + bf16_tof(l4.y);
        o.z = 0.25f * (s4[2] + p4[2]) + b4.z + bf16_tof(l4.z);
        o.w = 0.25f * (s4[3] + p4[3]) + b4.w + bf16_tof(l4.w);
        *(float4*)(out + (size_t)d * 128 + c0) = o;
    }
}

// ---------------------------------------------------------------------------

extern "C" void kernel_launch(void* const* d_in, const int* in_sizes, int n_in,
                              void* d_out, int out_size, void* d_ws, size_t ws_size,
                              hipStream_t stream)
{
    const float* x   = (const float*)d_in[0];
    const int*   ei  = (const int*)d_in[1];
    const float* W0  = (const float*)d_in[2];
    const float* as0 = (const float*)d_in[3];
    const float* ad0 = (const float*)d_in[4];
    const float* b0  = (const float*)d_in[5];
    const float* lw0 = (const float*)d_in[6];
    const float* lb0 = (const float*)d_in[7];
    const float* W1  = (const float*)d_in[8];
    const float* as1 = (const float*)d_in[9];
    const float* ad1 = (const float*)d_in[10];
    const float* b1  = (const float*)d_in[11];
    const float* lw1 = (const float*)d_in[12];
    const float* lb1 = (const float*)d_in[13];
    const float* W2  = (const float*)d_in[14];
    const float* as2 = (const float*)d_in[15];
    const float* ad2 = (const float*)d_in[16];
    const float* b2  = (const float*)d_in[17];
    const float* lw2 = (const float*)d_in[18];
    const float* lb2 = (const float*)d_in[19];
    float* out = (float*)d_out;

    const int N = in_sizes[0] / 256;
    const int E = in_sizes[1] / 2;
    const int* esrc = ei;
    const int* edst = ei + E;

    const int gm = (N + 127) / 128;          // 391
    const int gmp = ((gm + 7) / 8) * 8;      // 392 (XCD multiple)
    const size_t Agroups = (size_t)gm * 8;   // 16-row groups in padded A

    // ---- workspace layout ----
    char* p = (char*)d_ws;
    ushort* act_hi = (ushort*)p; p += Agroups * 8 * 512 * 2;   // packed, 25.6 MB
    ushort* act_lo = (ushort*)p; p += Agroups * 8 * 512 * 2;
    ushort* h      = (ushort*)p; p += (size_t)N * 512 * 2;
    ushort* lin    = (ushort*)p; p += (size_t)N * 256 * 2;
    float*  as_a   = (float*)p;  p += (size_t)N * 4 * 4;
    float*  ad_a   = (float*)p;  p += (size_t)N * 4 * 4;
    float*  as_b   = (float*)p;  p += (size_t)N * 4 * 4;
    float*  ad_b   = (float*)p;  p += (size_t)N * 4 * 4;
    ushort* B0h = (ushort*)p; p += (size_t)32 * 8 * 512 * 2;   // 512 rows packed
    ushort* B0l = (ushort*)p; p += (size_t)32 * 8 * 512 * 2;
    ushort* B1h = (ushort*)p; p += (size_t)32 * 8 * 512 * 2;
    ushort* B1l = (ushort*)p; p += (size_t)32 * 8 * 512 * 2;
    ushort* B2h = (ushort*)p; p += (size_t)40 * 8 * 512 * 2;   // 640 rows packed
    ushort* B2l = (ushort*)p; p += (size_t)40 * 8 * 512 * 2;
    float* vsd0 = (float*)p; p += 256 * 8 * 4;
    float* vsd1 = (float*)p; p += 256 * 8 * 4;
    float* vsd2 = (float*)p; p += 256 * 8 * 4;
    unsigned int* amax = (unsigned int*)p;      // 12 slots (4 per layer)
    int* deg    = (int*)(amax + 12);
    int* off    = deg + N;
    int* cursor = off + N + 1;
    int* csrc   = cursor + N;

    // ---- zero amax + deg + off + cursor in one memset ----
    hipMemsetAsync(amax, 0, sizeof(int) * (size_t)(3 * N + 13), stream);

    int egrid = (E + 255) / 256;
    int g4 = (N + 3) / 4;
    int g8 = (N + 7) / 8;

    // ---- merged: weight prep + att folds + degree count ----
    wprep_kernel<<<1676 + egrid, 256, 0, stream>>>(W0, lw0, W1, lw1, W2, lw2,
                                                   B0h, B0l, B1h, B1l, B2h, B2l,
                                                   as0, ad0, as1, ad1, as2, ad2,
                                                   vsd0, vsd1, vsd2,
                                                   edst, deg, E);
    scan_kernel<<<1, 1024, 0, stream>>>(deg, off, N);

    // ---- merged: scatter + (x -> packed + layer-0 dots + amax0) ----
    scatter_split_kernel<<<egrid + g8, 256, 0, stream>>>(esrc, edst, off, cursor, csrc, E, egrid,
                                                         x, vsd0, act_hi, act_lo, as_a, ad_a,
                                                         amax + 0, N);

    // ---- layer 0 ----
    gemm_mfma_kernel<<<gmp * 4, 256, 0, stream>>>(act_hi, act_lo, B0h, B0l, h, 256, lin, lb0, gm, N, 512);
    agg01_kernel<<<g8, 256, 0, stream>>>(h, as_a, ad_a, amax + 0, off, csrc, lin, b0,
                                         act_hi, act_lo, vsd1, as_b, ad_b, amax + 4, N);

    // ---- layer 1 ----
    gemm_mfma_kernel<<<gmp * 4, 256, 0, stream>>>(act_hi, act_lo, B1h, B1l, h, 256, lin, lb1, gm, N, 512);
    agg01_kernel<<<g8, 256, 0, stream>>>(h, as_b, ad_b, amax + 4, off, csrc, lin, b1,
                                         act_hi, act_lo, vsd2, as_a, ad_a, amax + 8, N);

    // ---- layer 2 ----
    gemm_mfma_kernel<<<gmp * 5, 256, 0, stream>>>(act_hi, act_lo, B2h, B2l, h, 512, lin, lb2, gm, N, 640);
    agg2_kernel<<<g4, 256, 0, stream>>>(h, as_a, ad_a, amax + 8, off, csrc, lin, b2, out, N);
}

// Round 9
// 683.547 us; speedup vs baseline: 1.6747x; 1.6747x over previous
//
#include <hip/hip_runtime.h>
#include <cstddef>

// ---------------------------------------------------------------------------
// GAT 3-layer pipeline, round 17.
// R17: revert R16's amax fusion — the smx/barrier/atomic epilogue in agg01
//   changed codegen (VGPR 36->32), serialized the batched gather loads, and
//   collapsed MLP (74.5 -> 306us, VALUBusy 28 -> 7%). amax is a separate tiny
//   kernel again. KEEP the benign grid merges: degree inside wprep, scatter
//   inside the split kernel (block-range branch, hot loops untouched).
// - GEMM (R15): A+B both LDS double-buffered (m97 structure), (256,2).
// - agg01 (R12/R14): two nodes/wave, ushort8 rows, x4 edge batch, (256,6).
// - split_att (R13): two nodes/wave, 5-round xor-tree, ushort8 stores.
// Packed layout (per matrix, rows padded to 128): group g=row>>4, chunk
// c=k>>5, lane l=(row&15)+16*((k&31)>>3), sub=k&7:
//   offset = (g*8+c)*512 + l*8 + sub   (ushorts)
// ---------------------------------------------------------------------------

typedef __bf16 bf16x8 __attribute__((ext_vector_type(8)));
typedef float floatx4 __attribute__((ext_vector_type(4)));
typedef unsigned short ushortx8 __attribute__((ext_vector_type(8)));

__device__ __forceinline__ unsigned short bf16_rn(float f) {
    unsigned int u = __float_as_uint(f);
    u += 0x7FFF + ((u >> 16) & 1);
    return (unsigned short)(u >> 16);
}
__device__ __forceinline__ float bf16_tof(unsigned short h) {
    return __uint_as_float(((unsigned int)h) << 16);
}

__device__ __forceinline__ float amax_decode(unsigned int u) {
    unsigned int bits = (u >> 31) ? (u & 0x7FFFFFFFu) : ~u;
    return __uint_as_float(bits);
}

// 16B-per-lane direct global->LDS copy: lds dest = base + lane*16 (HW rule).
__device__ __forceinline__ void gload_lds16(const void* g, void* l) {
    __builtin_amdgcn_global_load_lds(
        (const __attribute__((address_space(1))) unsigned int*)g,
        (__attribute__((address_space(3))) unsigned int*)l, 16, 0, 0);
}

// ---------------- CSR scan (single block) ----------------

__global__ __launch_bounds__(1024) void scan_kernel(const int* __restrict__ deg,
                                                    int* __restrict__ off, int n) {
    __shared__ int wsum[16];
    __shared__ int carry_s;
    int tid = threadIdx.x, lane = tid & 63, wid = tid >> 6;
    if (tid == 0) { carry_s = 0; off[0] = 0; }
    __syncthreads();
    for (int base = 0; base < n; base += 1024) {
        int i = base + tid;
        int v = (i < n) ? deg[i] : 0;
        int s = v;
        #pragma unroll
        for (int d = 1; d < 64; d <<= 1) {
            int t = __shfl_up(s, d, 64);
            if (lane >= d) s += t;
        }
        if (lane == 63) wsum[wid] = s;
        __syncthreads();
        if (wid == 0) {
            int wv = (lane < 16) ? wsum[lane] : 0;
            #pragma unroll
            for (int d = 1; d < 16; d <<= 1) {
                int t = __shfl_up(wv, d, 64);
                if (lane >= d) wv += t;
            }
            if (lane < 16) wsum[lane] = wv;
        }
        __syncthreads();
        int prev = (wid > 0) ? wsum[wid - 1] : 0;
        int inc = carry_s + prev + s;
        if (i < n) off[i + 1] = inc;
        int chunk_total = wsum[15];
        __syncthreads();
        if (tid == 0) carry_s += chunk_total;
        __syncthreads();
    }
}

// ---------------- merged: weight prep + att folds + degree count -------------

__global__ __launch_bounds__(256) void wprep_kernel(
    const float* __restrict__ W0, const float* __restrict__ lw0,
    const float* __restrict__ W1, const float* __restrict__ lw1,
    const float* __restrict__ W2, const float* __restrict__ lw2,
    ushort* __restrict__ B0h, ushort* __restrict__ B0l,
    ushort* __restrict__ B1h, ushort* __restrict__ B1l,
    ushort* __restrict__ B2h, ushort* __restrict__ B2l,
    const float* __restrict__ as0, const float* __restrict__ ad0,
    const float* __restrict__ as1, const float* __restrict__ ad1,
    const float* __restrict__ as2, const float* __restrict__ ad2,
    float* __restrict__ vsd0, float* __restrict__ vsd1, float* __restrict__ vsd2,
    const int* __restrict__ edst, int* __restrict__ deg, int E)
{
    int bid = blockIdx.x, tid = threadIdx.x;
    if (bid < 1664) {
        const float* src; ushort* dh; ushort* dl; int Ncols, roff, base;
        if (bid < 256)       { src = W0;  dh = B0h; dl = B0l; Ncols = 256; roff = 0;   base = 0; }
        else if (bid < 512)  { src = lw0; dh = B0h; dl = B0l; Ncols = 256; roff = 256; base = 256; }
        else if (bid < 768)  { src = W1;  dh = B1h; dl = B1l; Ncols = 256; roff = 0;   base = 512; }
        else if (bid < 1024) { src = lw1; dh = B1h; dl = B1l; Ncols = 256; roff = 256; base = 768; }
        else if (bid < 1536) { src = W2;  dh = B2h; dl = B2l; Ncols = 512; roff = 0;   base = 1024; }
        else                 { src = lw2; dh = B2h; dl = B2l; Ncols = 128; roff = 512; base = 1536; }
        int idx = (bid - base) * 256 + tid;
        int k = idx / Ncols, n = idx - k * Ncols;
        float v = src[idx];
        unsigned short hi = bf16_rn(v);
        unsigned short lo = bf16_rn(v - bf16_tof(hi));
        int row = n + roff;
        int poff = ((row >> 4) * 8 + (k >> 5)) * 512 + (((row & 15) + 16 * ((k & 31) >> 3)) << 3) + (k & 7);
        dh[poff] = hi;
        dl[poff] = lo;
    } else if (bid < 1676) {
        int fj = (bid - 1664) >> 2;
        int idx = ((bid - 1664) & 3) * 256 + tid;   // 0..1023 = K*H
        const float *W, *as_, *ad_; float* vsd; int C;
        if (fj == 0)      { W = W0; as_ = as0; ad_ = ad0; vsd = vsd0; C = 64; }
        else if (fj == 1) { W = W1; as_ = as1; ad_ = ad1; vsd = vsd1; C = 64; }
        else              { W = W2; as_ = as2; ad_ = ad2; vsd = vsd2; C = 128; }
        int k = idx >> 2, hh = idx & 3;
        const float* wp = W + (size_t)k * (4 * C) + hh * C;
        float s = 0.f, d = 0.f;
        for (int c = 0; c < C; c++) {
            float w = wp[c];
            s += w * as_[hh * C + c];
            d += w * ad_[hh * C + c];
        }
        vsd[k * 8 + hh] = s;       // vsd layout: [k][8] = 4 src then 4 dst
        vsd[k * 8 + 4 + hh] = d;
    } else {
        int e = (bid - 1676) * 256 + tid;
        if (e < E) atomicAdd(&deg[edst[e]], 1);
    }
}

// ---------------- merged: scatter + (x -> packed bf16 + layer-0 dots) --------
// Blocks [0, egrid): CSR scatter. Blocks [egrid, ...): split_att, two nodes
// per wave (32 lanes/node, 8 floats/lane), 5-round xor-tree, ushort8 stores.

__global__ __launch_bounds__(256, 6) void scatter_split_kernel(
    const int* __restrict__ esrc, const int* __restrict__ edst,
    const int* __restrict__ off, int* __restrict__ cursor,
    int* __restrict__ csrc, int E, int egrid,
    const float* __restrict__ x, const float* __restrict__ vsd,
    ushort* __restrict__ Aph, ushort* __restrict__ Apl,
    float* __restrict__ asrc, float* __restrict__ adst, int n)
{
    int bid = blockIdx.x;
    if (bid < egrid) {
        int e = bid * 256 + threadIdx.x;
        if (e < E) {
            int d = edst[e];
            int p = off[d] + atomicAdd(&cursor[d], 1);
            csrc[p] = esrc[e];
        }
        return;
    }
    int sb = bid - egrid;
    int wid = threadIdx.x >> 6, lane = threadIdx.x & 63;
    int half = lane >> 5, sl = lane & 31;
    int d = sb * 8 + wid * 2 + half;
    if (d >= n) return;
    int k0 = sl * 8;
    float4 va = *(const float4*)(x + (size_t)d * 256 + k0);
    float4 vb = *(const float4*)(x + (size_t)d * 256 + k0 + 4);
    float v[8] = {va.x, va.y, va.z, va.w, vb.x, vb.y, vb.z, vb.w};

    ushortx8 hi, lo;
    #pragma unroll
    for (int j = 0; j < 8; ++j) {
        unsigned short h8 = bf16_rn(v[j]);
        hi[j] = h8;
        lo[j] = bf16_rn(v[j] - bf16_tof(h8));
    }
    int poff = ((d >> 4) * 8 + (k0 >> 5)) * 512 + (((d & 15) + 16 * ((k0 & 31) >> 3)) << 3);
    *(ushortx8*)(Aph + poff) = hi;
    *(ushortx8*)(Apl + poff) = lo;

    // attention dots: pa/pb[h] = sum_k v[k] * vsd[k][h] (+4 for dst)
    const float* vp = vsd + (size_t)k0 * 8;
    float pa[4] = {0.f, 0.f, 0.f, 0.f}, pb[4] = {0.f, 0.f, 0.f, 0.f};
    #pragma unroll
    for (int r = 0; r < 8; ++r) {
        float4 ra = *(const float4*)(vp + r * 8);
        float4 rb = *(const float4*)(vp + r * 8 + 4);
        pa[0] += v[r] * ra.x; pa[1] += v[r] * ra.y;
        pa[2] += v[r] * ra.z; pa[3] += v[r] * ra.w;
        pb[0] += v[r] * rb.x; pb[1] += v[r] * rb.y;
        pb[2] += v[r] * rb.z; pb[3] += v[r] * rb.w;
    }
    #pragma unroll
    for (int o = 1; o < 32; o <<= 1) {
        #pragma unroll
        for (int j = 0; j < 4; ++j) {
            pa[j] += __shfl_xor(pa[j], o, 64);
            pb[j] += __shfl_xor(pb[j], o, 64);
        }
    }
    if (sl == 0) {
        *(float4*)(asrc + (size_t)d * 4) = make_float4(pa[0], pa[1], pa[2], pa[3]);
        *(float4*)(adst + (size_t)d * 4) = make_float4(pb[0], pb[1], pb[2], pb[3]);
    }
}

// per-head global max of asrc (order-preserving uint encoding)
__global__ __launch_bounds__(256) void amax_kernel(const float* __restrict__ asrc,
                                                   unsigned int* __restrict__ amax, int n) {
    int tid = threadIdx.x;
    float4 m4 = make_float4(-1e30f, -1e30f, -1e30f, -1e30f);
    for (int i = blockIdx.x * 256 + tid; i < n; i += gridDim.x * 256) {
        float4 v = ((const float4*)asrc)[i];
        m4.x = fmaxf(m4.x, v.x); m4.y = fmaxf(m4.y, v.y);
        m4.z = fmaxf(m4.z, v.z); m4.w = fmaxf(m4.w, v.w);
    }
    #pragma unroll
    for (int o = 32; o > 0; o >>= 1) {
        m4.x = fmaxf(m4.x, __shfl_down(m4.x, o, 64));
        m4.y = fmaxf(m4.y, __shfl_down(m4.y, o, 64));
        m4.z = fmaxf(m4.z, __shfl_down(m4.z, o, 64));
        m4.w = fmaxf(m4.w, __shfl_down(m4.w, o, 64));
    }
    __shared__ float sm[4][4];
    int wid = tid >> 6, lane = tid & 63;
    if (lane == 0) { sm[wid][0] = m4.x; sm[wid][1] = m4.y; sm[wid][2] = m4.z; sm[wid][3] = m4.w; }
    __syncthreads();
    if (tid < 4) {
        float v = fmaxf(fmaxf(sm[0][tid], sm[1][tid]), fmaxf(sm[2][tid], sm[3][tid]));
        unsigned int u = __float_as_uint(v);
        u = (u >> 31) ? ~u : (u | 0x80000000u);
        atomicMax(&amax[tid], u);
    }
}

// ---------------- LDS MFMA GEMM on packed operands (m97 structure) -----------
// BM=BN=128, 4 waves (64x64 each), K=256 in 8 chunks of 32.
// Per chunk 32KB LDS: [A-hi 8K | A-lo 8K | B-hi 8K | B-lo 8K], double-buffered
// (64KB). Wave w stages region w: 8 x 1KB gload_lds16 per chunk.

__global__ __launch_bounds__(256, 2) void gemm_mfma_kernel(
    const ushort* __restrict__ Aph, const ushort* __restrict__ Apl,
    const ushort* __restrict__ Bph, const ushort* __restrict__ Bpl,
    ushort* __restrict__ O1, int n1, ushort* __restrict__ O2,
    const float* __restrict__ bias2,
    int gm, int M, int N)
{
    __shared__ __align__(16) char smem[65536];   // 2 buffers x 32KB
    int gy = N >> 7;
    int bid = blockIdx.x;
    int k8 = bid & 7, sb = bid >> 3;
    int ny = sb % gy, bxi = sb / gy;
    int bx = bxi * 8 + k8;
    if (bx >= gm) return;
    int bm = bx * 128, bn = ny * 128;

    int tid = threadIdx.x, lane = tid & 63, wv = tid >> 6;
    int wm = (wv >> 1) * 64, wn = (wv & 1) * 64;
    int fr = lane & 15, q = lane >> 4;

    // staging role: wave 0 -> A-hi, 1 -> A-lo, 2 -> B-hi, 3 -> B-lo
    const ushort* sp;
    size_t gbase;
    if (wv == 0)      { sp = Aph; gbase = (size_t)(bm >> 4) * 4096; }
    else if (wv == 1) { sp = Apl; gbase = (size_t)(bm >> 4) * 4096; }
    else if (wv == 2) { sp = Bph; gbase = (size_t)(bn >> 4) * 4096; }
    else              { sp = Bpl; gbase = (size_t)(bn >> 4) * 4096; }
    size_t gsrc = gbase + (size_t)lane * 8;   // ushort offset; 16B per lane
    int lbase = wv * 8192;                    // byte offset of this wave's region

    int agl = (wv >> 1) * 4;   // A group base for reads (= wm/16)
    int bgl = (wv & 1) * 4;    // B group base for reads (= wn/16)

    floatx4 acc[4][4] = {};

    // prologue: stage chunk 0 into buffer 0 (8 x 1KB per wave)
    #pragma unroll
    for (int t = 0; t < 8; ++t)
        gload_lds16(sp + gsrc + (size_t)t * 4096, smem + lbase + t * 1024);
    __syncthreads();

    #pragma unroll
    for (int it = 0; it < 8; ++it) {
        int cur = (it & 1) << 15;   // 0 / 32768
        if (it < 7) {
            int nb = ((it + 1) & 1) << 15;
            size_t co = gsrc + (size_t)(it + 1) * 512;
            #pragma unroll
            for (int t = 0; t < 8; ++t)
                gload_lds16(sp + co + (size_t)t * 4096, smem + nb + lbase + t * 1024);
        }
        bf16x8 cah[4], cal[4], cbh[4], cbl[4];
        #pragma unroll
        for (int i = 0; i < 4; ++i) {
            cah[i] = *(const bf16x8*)(smem + cur + (agl + i) * 1024 + lane * 16);
            cal[i] = *(const bf16x8*)(smem + cur + 8192 + (agl + i) * 1024 + lane * 16);
            cbh[i] = *(const bf16x8*)(smem + cur + 16384 + (bgl + i) * 1024 + lane * 16);
            cbl[i] = *(const bf16x8*)(smem + cur + 24576 + (bgl + i) * 1024 + lane * 16);
        }
        #pragma unroll
        for (int i = 0; i < 4; ++i)
            #pragma unroll
            for (int j = 0; j < 4; ++j) {
                acc[i][j] = __builtin_amdgcn_mfma_f32_16x16x32_bf16(cah[i], cbh[j], acc[i][j], 0, 0, 0);
                acc[i][j] = __builtin_amdgcn_mfma_f32_16x16x32_bf16(cah[i], cbl[j], acc[i][j], 0, 0, 0);
                acc[i][j] = __builtin_amdgcn_mfma_f32_16x16x32_bf16(cal[i], cbh[j], acc[i][j], 0, 0, 0);
            }
        if (it < 7) __syncthreads();
    }

    // ---- C store (C/D layout: col=lane&15, row=(lane>>4)*4+reg) ----
    int n2 = N - n1;
    #pragma unroll
    for (int i = 0; i < 4; ++i) {
        #pragma unroll
        for (int r = 0; r < 4; ++r) {
            int grow = bm + wm + i * 16 + q * 4 + r;
            if (grow < M) {
                #pragma unroll
                for (int j = 0; j < 4; ++j) {
                    int gcol = bn + wn + j * 16 + fr;
                    float v = acc[i][j][r];
                    if (gcol < n1) {
                        O1[(size_t)grow * n1 + gcol] = bf16_rn(v);
                    } else {
                        v += bias2[gcol - n1];
                        O2[(size_t)grow * n2 + (gcol - n1)] = bf16_rn(v);
                    }
                }
            }
        }
    }
}

// ---------------- aggregation layers 0/1: TWO nodes per wave -----------------
// 32 lanes per node, 8 cols/lane (ushort8 16B row loads), x4 edge batch ->
// 8 gather chains in flight per wave. No barriers / no LDS — keep the
// register allocator free to hold all 4 row buffers (R16 lesson).

__global__ __launch_bounds__(256, 6) void agg01_kernel(
    const ushort* __restrict__ h,    // [N,256] bf16
    const float* __restrict__ asrc, const float* __restrict__ adst,
    const unsigned int* __restrict__ amax,
    const int* __restrict__ off, const int* __restrict__ csrc,
    const ushort* __restrict__ lin,  // [N,256] bf16 (lb applied in GEMM)
    const float* __restrict__ bias,  // [256]
    ushort* __restrict__ Aph, ushort* __restrict__ Apl,   // packed act out
    const float* __restrict__ vsd_next,                   // [256][8]
    float* __restrict__ asrc_out, float* __restrict__ adst_out,
    int n)
{
    int wid = threadIdx.x >> 6, lane = threadIdx.x & 63;
    int half = lane >> 5, sl = lane & 31;
    int d = blockIdx.x * 8 + wid * 2 + half;
    bool valid = (d < n);
    int dd = valid ? d : (n - 1);
    int head = sl >> 3;          // 8 lanes per head; head = c0>>6
    int c0 = sl * 8;             // 8 cols per lane
    float a_d = adst[dd * 4 + head];
    float mh = amax_decode(amax[head]) + a_d;
    float m = (mh > 0.f) ? mh : 0.2f * mh;   // >= true segment max
    int s0 = off[dd], s1 = valid ? off[dd + 1] : s0;

    float denom = 0.f;
    float ac[8] = {0.f, 0.f, 0.f, 0.f, 0.f, 0.f, 0.f, 0.f};
    int i = s0;
    for (; i + 4 <= s1; i += 4) {
        int sa = csrc[i], sb = csrc[i + 1], sc = csrc[i + 2], sd = csrc[i + 3];
        float ea = asrc[sa * 4 + head];
        float eb = asrc[sb * 4 + head];
        float ec = asrc[sc * 4 + head];
        float ed = asrc[sd * 4 + head];
        ushortx8 hva = *(const ushortx8*)(h + (size_t)sa * 256 + c0);
        ushortx8 hvb = *(const ushortx8*)(h + (size_t)sb * 256 + c0);
        ushortx8 hvc = *(const ushortx8*)(h + (size_t)sc * 256 + c0);
        ushortx8 hvd = *(const ushortx8*)(h + (size_t)sd * 256 + c0);
        ea += a_d; ea = (ea > 0.f) ? ea : 0.2f * ea; float wa = __expf(ea - m);
        eb += a_d; eb = (eb > 0.f) ? eb : 0.2f * eb; float wb = __expf(eb - m);
        ec += a_d; ec = (ec > 0.f) ? ec : 0.2f * ec; float wc = __expf(ec - m);
        ed += a_d; ed = (ed > 0.f) ? ed : 0.2f * ed; float wd = __expf(ed - m);
        denom += wa;
        #pragma unroll
        for (int j = 0; j < 8; ++j) ac[j] += wa * bf16_tof(hva[j]);
        denom += wb;
        #pragma unroll
        for (int j = 0; j < 8; ++j) ac[j] += wb * bf16_tof(hvb[j]);
        denom += wc;
        #pragma unroll
        for (int j = 0; j < 8; ++j) ac[j] += wc * bf16_tof(hvc[j]);
        denom += wd;
        #pragma unroll
        for (int j = 0; j < 8; ++j) ac[j] += wd * bf16_tof(hvd[j]);
    }
    for (; i < s1; ++i) {
        int s = csrc[i];
        float e = asrc[s * 4 + head] + a_d;
        e = (e > 0.f) ? e : 0.2f * e;
        float w = __expf(e - m);
        denom += w;
        ushortx8 hv = *(const ushortx8*)(h + (size_t)s * 256 + c0);
        #pragma unroll
        for (int j = 0; j < 8; ++j) ac[j] += w * bf16_tof(hv[j]);
    }

    if (valid) {
        float inv = 1.f / (denom + 1e-16f);
        float4 b4a = *(const float4*)(bias + c0);
        float4 b4b = *(const float4*)(bias + c0 + 4);
        ushortx8 l8 = *(const ushortx8*)(lin + (size_t)dd * 256 + c0);
        float v[8];
        v[0] = ac[0] * inv + b4a.x + bf16_tof(l8[0]);
        v[1] = ac[1] * inv + b4a.y + bf16_tof(l8[1]);
        v[2] = ac[2] * inv + b4a.z + bf16_tof(l8[2]);
        v[3] = ac[3] * inv + b4a.w + bf16_tof(l8[3]);
        v[4] = ac[4] * inv + b4b.x + bf16_tof(l8[4]);
        v[5] = ac[5] * inv + b4b.y + bf16_tof(l8[5]);
        v[6] = ac[6] * inv + b4b.z + bf16_tof(l8[6]);
        v[7] = ac[7] * inv + b4b.w + bf16_tof(l8[7]);
        #pragma unroll
        for (int j = 0; j < 8; ++j)
            v[j] = (v[j] > 0.f) ? v[j] : (__expf(v[j]) - 1.f);   // ELU

        // packed act write (8 consecutive k in one 16B store)
        ushortx8 oh, ol;
        #pragma unroll
        for (int j = 0; j < 8; ++j) {
            unsigned short hi = bf16_rn(v[j]);
            oh[j] = hi;
            ol[j] = bf16_rn(v[j] - bf16_tof(hi));
        }
        int poff = ((dd >> 4) * 8 + (c0 >> 5)) * 512 + (((dd & 15) + 16 * ((c0 & 31) >> 3)) << 3);
        *(ushortx8*)(Aph + poff) = oh;
        *(ushortx8*)(Apl + poff) = ol;

        // fused next-layer attention dots (act-derived, exact fp32 values)
        const float* vp = vsd_next + (size_t)c0 * 8;
        float pa[4] = {0.f, 0.f, 0.f, 0.f}, pb[4] = {0.f, 0.f, 0.f, 0.f};
        #pragma unroll
        for (int r = 0; r < 8; ++r) {
            float4 ra = *(const float4*)(vp + r * 8);
            float4 rb = *(const float4*)(vp + r * 8 + 4);
            pa[0] += v[r] * ra.x; pa[1] += v[r] * ra.y;
            pa[2] += v[r] * ra.z; pa[3] += v[r] * ra.w;
            pb[0] += v[r] * rb.x; pb[1] += v[r] * rb.y;
            pb[2] += v[r] * rb.z; pb[3] += v[r] * rb.w;
        }
        #pragma unroll
        for (int o = 1; o < 32; o <<= 1) {
            #pragma unroll
            for (int j = 0; j < 4; ++j) {
                pa[j] += __shfl_xor(pa[j], o, 64);
                pb[j] += __shfl_xor(pb[j], o, 64);
            }
        }
        if (sl == 0) {
            *(float4*)(asrc_out + (size_t)dd * 4) = make_float4(pa[0], pa[1], pa[2], pa[3]);
            *(float4*)(adst_out + (size_t)dd * 4) = make_float4(pb[0], pb[1], pb[2], pb[3]);
        }
    }
}

// ---------------- aggregation layer 2: wave-per-node, mean heads -------------
// Edge loop batched x4 (8 row-loads in flight).

__global__ __launch_bounds__(256, 6) void agg2_kernel(
    const ushort* __restrict__ h,    // [N,512] bf16
    const float* __restrict__ asrc, const float* __restrict__ adst,
    const unsigned int* __restrict__ amax,
    const int* __restrict__ off, const int* __restrict__ csrc,
    const ushort* __restrict__ lin,  // [N,128] bf16 (lb2 applied in GEMM)
    const float* __restrict__ bias,  // [128]
    float* __restrict__ out,         // [N,128]
    int n)
{
    int wid = threadIdx.x >> 6, lane = threadIdx.x & 63;
    int d = blockIdx.x * 4 + wid;
    if (d >= n) return;
    int ha = lane >> 5;
    int hb = ha + 2;
    int c0 = lane * 4;
    float ad_a = adst[d * 4 + ha];
    float ad_b = adst[d * 4 + hb];
    float mha = amax_decode(amax[ha]) + ad_a;
    float mhb = amax_decode(amax[hb]) + ad_b;
    float ma = (mha > 0.f) ? mha : 0.2f * mha;
    float mb = (mhb > 0.f) ? mhb : 0.2f * mhb;
    int s0 = off[d], s1 = off[d + 1];

    float da = 0.f, db = 0.f;
    floatx4 aa = {0.f, 0.f, 0.f, 0.f}, ab = {0.f, 0.f, 0.f, 0.f};
    int i = s0;
    for (; i + 4 <= s1; i += 4) {
        int sw = csrc[i], sx = csrc[i + 1], sy = csrc[i + 2], sz = csrc[i + 3];
        float ea0 = asrc[sw * 4 + ha], eb0 = asrc[sw * 4 + hb];
        float ea1 = asrc[sx * 4 + ha], eb1 = asrc[sx * 4 + hb];
        float ea2 = asrc[sy * 4 + ha], eb2 = asrc[sy * 4 + hb];
        float ea3 = asrc[sz * 4 + ha], eb3 = asrc[sz * 4 + hb];
        ushort4 va0 = *(const ushort4*)(h + (size_t)sw * 512 + c0);
        ushort4 vb0 = *(const ushort4*)(h + (size_t)sw * 512 + 256 + c0);
        ushort4 va1 = *(const ushort4*)(h + (size_t)sx * 512 + c0);
        ushort4 vb1 = *(const ushort4*)(h + (size_t)sx * 512 + 256 + c0);
        ushort4 va2 = *(const ushort4*)(h + (size_t)sy * 512 + c0);
        ushort4 vb2 = *(const ushort4*)(h + (size_t)sy * 512 + 256 + c0);
        ushort4 va3 = *(const ushort4*)(h + (size_t)sz * 512 + c0);
        ushort4 vb3 = *(const ushort4*)(h + (size_t)sz * 512 + 256 + c0);
        ea0 += ad_a; ea0 = (ea0 > 0.f) ? ea0 : 0.2f * ea0; float wa0 = __expf(ea0 - ma);
        eb0 += ad_b; eb0 = (eb0 > 0.f) ? eb0 : 0.2f * eb0; float wb0 = __expf(eb0 - mb);
        ea1 += ad_a; ea1 = (ea1 > 0.f) ? ea1 : 0.2f * ea1; float wa1 = __expf(ea1 - ma);
        eb1 += ad_b; eb1 = (eb1 > 0.f) ? eb1 : 0.2f * eb1; float wb1 = __expf(eb1 - mb);
        ea2 += ad_a; ea2 = (ea2 > 0.f) ? ea2 : 0.2f * ea2; float wa2 = __expf(ea2 - ma);
        eb2 += ad_b; eb2 = (eb2 > 0.f) ? eb2 : 0.2f * eb2; float wb2 = __expf(eb2 - mb);
        ea3 += ad_a; ea3 = (ea3 > 0.f) ? ea3 : 0.2f * ea3; float wa3 = __expf(ea3 - ma);
        eb3 += ad_b; eb3 = (eb3 > 0.f) ? eb3 : 0.2f * eb3; float wb3 = __expf(eb3 - mb);
        da += wa0; db += wb0;
        aa[0] += wa0 * bf16_tof(va0.x); aa[1] += wa0 * bf16_tof(va0.y);
        aa[2] += wa0 * bf16_tof(va0.z); aa[3] += wa0 * bf16_tof(va0.w);
        ab[0] += wb0 * bf16_tof(vb0.x); ab[1] += wb0 * bf16_tof(vb0.y);
        ab[2] += wb0 * bf16_tof(vb0.z); ab[3] += wb0 * bf16_tof(vb0.w);
        da += wa1; db += wb1;
        aa[0] += wa1 * bf16_tof(va1.x); aa[1] += wa1 * bf16_tof(va1.y);
        aa[2] += wa1 * bf16_tof(va1.z); aa[3] += wa1 * bf16_tof(va1.w);
        ab[0] += wb1 * bf16_tof(vb1.x); ab[1] += wb1 * bf16_tof(vb1.y);
        ab[2] += wb1 * bf16_tof(vb1.z); ab[3] += wb1 * bf16_tof(vb1.w);
        da += wa2; db += wb2;
        aa[0] += wa2 * bf16_tof(va2.x); aa[1] += wa2 * bf16_tof(va2.y);
        aa[2] += wa2 * bf16_tof(va2.z); aa[3] += wa2 * bf16_tof(va2.w);
        ab[0] += wb2 * bf16_tof(vb2.x); ab[1] += wb2 * bf16_tof(vb2.y);
        ab[2] += wb2 * bf16_tof(vb2.z); ab[3] += wb2 * bf16_tof(vb2.w);
        da += wa3; db += wb3;
        aa[0] += wa3 * bf16_tof(va3.x); aa[1] += wa3 * bf16_tof(va3.y);
        aa[2] += wa3 * bf16_tof(va3.z); aa[3] += wa3 * bf16_tof(va3.w);
        ab[0] += wb3 * bf16_tof(vb3.x); ab[1] += wb3 * bf16_tof(vb3.y);
        ab[2] += wb3 * bf16_tof(vb3.z); ab[3] += wb3 * bf16_tof(vb3.w);
    }
    for (; i < s1; ++i) {
        int s = csrc[i];
        float ea = asrc[s * 4 + ha] + ad_a;
        float eb = asrc[s * 4 + hb] + ad_b;
        ea = (ea > 0.f) ? ea : 0.2f * ea;
        eb = (eb > 0.f) ? eb : 0.2f * eb;
        float wa = __expf(ea - ma), wb = __expf(eb - mb);
        da += wa; db += wb;
        ushort4 va = *(const ushort4*)(h + (size_t)s * 512 + c0);
        ushort4 vb = *(const ushort4*)(h + (size_t)s * 512 + 256 + c0);
        aa[0] += wa * bf16_tof(va.x); aa[1] += wa * bf16_tof(va.y);
        aa[2] += wa * bf16_tof(va.z); aa[3] += wa * bf16_tof(va.w);
        ab[0] += wb * bf16_tof(vb.x); ab[1] += wb * bf16_tof(vb.y);
        ab[2] += wb * bf16_tof(vb.z); ab[3] += wb * bf16_tof(vb.w);
    }
    float ia = 1.f / (da + 1e-16f), ib = 1.f / (db + 1e-16f);
    float s4[4];
    #pragma unroll
    for (int j = 0; j < 4; ++j) s4[j] = aa[j] * ia + ab[j] * ib;
    float p4[4];
    #pragma unroll
    for (int j = 0; j < 4; ++j) p4[j] = __shfl_xor(s4[j], 32, 64);
    if (lane < 32) {
        float4 b4 = *(const float4*)(bias + c0);
        ushort4 l4 = *(const ushort4*)(lin + (size_t)d * 128 + c0);
        float4 o;
        o.x = 0.25f * (s4[0] + p4[0]) + b4.x + bf16_tof(l4.x);
        o.y = 0.25f * (s4[1] + p4[1]) + b4.y + bf16_tof(l4.y);
        o.z = 0.25f * (s4[2] + p4[2]) + b4.z + bf16_tof(l4.z);
        o.w = 0.25f * (s4[3] + p4[3]) + b4.w + bf16_tof(l4.w);
        *(float4*)(out + (size_t)d * 128 + c0) = o;
    }
}

// ---------------------------------------------------------------------------

extern "C" void kernel_launch(void* const* d_in, const int* in_sizes, int n_in,
                              void* d_out, int out_size, void* d_ws, size_t ws_size,
                              hipStream_t stream)
{
    const float* x   = (const float*)d_in[0];
    const int*   ei  = (const int*)d_in[1];
    const float* W0  = (const float*)d_in[2];
    const float* as0 = (const float*)d_in[3];
    const float* ad0 = (const float*)d_in[4];
    const float* b0  = (const float*)d_in[5];
    const float* lw0 = (const float*)d_in[6];
    const float* lb0 = (const float*)d_in[7];
    const float* W1  = (const float*)d_in[8];
    const float* as1 = (const float*)d_in[9];
    const float* ad1 = (const float*)d_in[10];
    const float* b1  = (const float*)d_in[11];
    const float* lw1 = (const float*)d_in[12];
    const float* lb1 = (const float*)d_in[13];
    const float* W2  = (const float*)d_in[14];
    const float* as2 = (const float*)d_in[15];
    const float* ad2 = (const float*)d_in[16];
    const float* b2  = (const float*)d_in[17];
    const float* lw2 = (const float*)d_in[18];
    const float* lb2 = (const float*)d_in[19];
    float* out = (float*)d_out;

    const int N = in_sizes[0] / 256;
    const int E = in_sizes[1] / 2;
    const int* esrc = ei;
    const int* edst = ei + E;

    const int gm = (N + 127) / 128;          // 391
    const int gmp = ((gm + 7) / 8) * 8;      // 392 (XCD multiple)
    const size_t Agroups = (size_t)gm * 8;   // 16-row groups in padded A

    // ---- workspace layout ----
    char* p = (char*)d_ws;
    ushort* act_hi = (ushort*)p; p += Agroups * 8 * 512 * 2;   // packed, 25.6 MB
    ushort* act_lo = (ushort*)p; p += Agroups * 8 * 512 * 2;
    ushort* h      = (ushort*)p; p += (size_t)N * 512 * 2;
    ushort* lin    = (ushort*)p; p += (size_t)N * 256 * 2;
    float*  as_a   = (float*)p;  p += (size_t)N * 4 * 4;
    float*  ad_a   = (float*)p;  p += (size_t)N * 4 * 4;
    float*  as_b   = (float*)p;  p += (size_t)N * 4 * 4;
    float*  ad_b   = (float*)p;  p += (size_t)N * 4 * 4;
    ushort* B0h = (ushort*)p; p += (size_t)32 * 8 * 512 * 2;   // 512 rows packed
    ushort* B0l = (ushort*)p; p += (size_t)32 * 8 * 512 * 2;
    ushort* B1h = (ushort*)p; p += (size_t)32 * 8 * 512 * 2;
    ushort* B1l = (ushort*)p; p += (size_t)32 * 8 * 512 * 2;
    ushort* B2h = (ushort*)p; p += (size_t)40 * 8 * 512 * 2;   // 640 rows packed
    ushort* B2l = (ushort*)p; p += (size_t)40 * 8 * 512 * 2;
    float* vsd0 = (float*)p; p += 256 * 8 * 4;
    float* vsd1 = (float*)p; p += 256 * 8 * 4;
    float* vsd2 = (float*)p; p += 256 * 8 * 4;
    unsigned int* amax = (unsigned int*)p;      // 12 slots (4 per layer)
    int* deg    = (int*)(amax + 12);
    int* off    = deg + N;
    int* cursor = off + N + 1;
    int* csrc   = cursor + N;

    // ---- zero amax + deg + off + cursor in one memset ----
    hipMemsetAsync(amax, 0, sizeof(int) * (size_t)(3 * N + 13), stream);

    int egrid = (E + 255) / 256;
    int g4 = (N + 3) / 4;
    int g8 = (N + 7) / 8;

    // ---- merged: weight prep + att folds + degree count ----
    wprep_kernel<<<1676 + egrid, 256, 0, stream>>>(W0, lw0, W1, lw1, W2, lw2,
                                                   B0h, B0l, B1h, B1l, B2h, B2l,
                                                   as0, ad0, as1, ad1, as2, ad2,
                                                   vsd0, vsd1, vsd2,
                                                   edst, deg, E);
    scan_kernel<<<1, 1024, 0, stream>>>(deg, off, N);

    // ---- merged: scatter + (x -> packed + layer-0 dots) ----
    scatter_split_kernel<<<egrid + g8, 256, 0, stream>>>(esrc, edst, off, cursor, csrc, E, egrid,
                                                         x, vsd0, act_hi, act_lo, as_a, ad_a, N);
    amax_kernel<<<32, 256, 0, stream>>>(as_a, amax + 0, N);

    // ---- layer 0 ----
    gemm_mfma_kernel<<<gmp * 4, 256, 0, stream>>>(act_hi, act_lo, B0h, B0l, h, 256, lin, lb0, gm, N, 512);
    agg01_kernel<<<g8, 256, 0, stream>>>(h, as_a, ad_a, amax + 0, off, csrc, lin, b0,
                                         act_hi, act_lo, vsd1, as_b, ad_b, N);
    amax_kernel<<<32, 256, 0, stream>>>(as_b, amax + 4, N);

    // ---- layer 1 ----
    gemm_mfma_kernel<<<gmp * 4, 256, 0, stream>>>(act_hi, act_lo, B1h, B1l, h, 256, lin, lb1, gm, N, 512);
    agg01_kernel<<<g8, 256, 0, stream>>>(h, as_b, ad_b, amax + 4, off, csrc, lin, b1,
                                         act_hi, act_lo, vsd2, as_a, ad_a, N);
    amax_kernel<<<32, 256, 0, stream>>>(as_a, amax + 8, N);

    // ---- layer 2 ----
    gemm_mfma_kernel<<<gmp * 5, 256, 0, stream>>>(act_hi, act_lo, B2h, B2l, h, 512, lin, lb2, gm, N, 640);
    agg2_kernel<<<g4, 256, 0, stream>>>(h, as_a, ad_a, amax + 8, off, csrc, lin, b2, out, N);
}

// Round 10
// 678.571 us; speedup vs baseline: 1.6870x; 1.0073x over previous
//
#include <hip/hip_runtime.h>
#include <cstddef>

// ---------------------------------------------------------------------------
// GAT 3-layer pipeline, round 18.
// R18: predicated full-batch edge loops in agg01/agg2 — ceil(deg/4) batches,
//   masked slots clamp index to s1-1 (L1-hit dup row) and force w=0. Removes
//   the avg ~1.5 serial tail chains per node (the dependent-latency third of
//   agg01's critical path). Accumulation order preserved; masked terms +0.0f.
// R17 base: amax separate; grid merges (degree in wprep, scatter in split);
//   GEMM (R15) A+B LDS double-buffered; agg01 two nodes/wave (256,6).
// Packed layout (per matrix, rows padded to 128): group g=row>>4, chunk
// c=k>>5, lane l=(row&15)+16*((k&31)>>3), sub=k&7:
//   offset = (g*8+c)*512 + l*8 + sub   (ushorts)
// ---------------------------------------------------------------------------

typedef __bf16 bf16x8 __attribute__((ext_vector_type(8)));
typedef float floatx4 __attribute__((ext_vector_type(4)));
typedef unsigned short ushortx8 __attribute__((ext_vector_type(8)));

__device__ __forceinline__ unsigned short bf16_rn(float f) {
    unsigned int u = __float_as_uint(f);
    u += 0x7FFF + ((u >> 16) & 1);
    return (unsigned short)(u >> 16);
}
__device__ __forceinline__ float bf16_tof(unsigned short h) {
    return __uint_as_float(((unsigned int)h) << 16);
}

__device__ __forceinline__ float amax_decode(unsigned int u) {
    unsigned int bits = (u >> 31) ? (u & 0x7FFFFFFFu) : ~u;
    return __uint_as_float(bits);
}

// 16B-per-lane direct global->LDS copy: lds dest = base + lane*16 (HW rule).
__device__ __forceinline__ void gload_lds16(const void* g, void* l) {
    __builtin_amdgcn_global_load_lds(
        (const __attribute__((address_space(1))) unsigned int*)g,
        (__attribute__((address_space(3))) unsigned int*)l, 16, 0, 0);
}

// ---------------- CSR scan (single block) ----------------

__global__ __launch_bounds__(1024) void scan_kernel(const int* __restrict__ deg,
                                                    int* __restrict__ off, int n) {
    __shared__ int wsum[16];
    __shared__ int carry_s;
    int tid = threadIdx.x, lane = tid & 63, wid = tid >> 6;
    if (tid == 0) { carry_s = 0; off[0] = 0; }
    __syncthreads();
    for (int base = 0; base < n; base += 1024) {
        int i = base + tid;
        int v = (i < n) ? deg[i] : 0;
        int s = v;
        #pragma unroll
        for (int d = 1; d < 64; d <<= 1) {
            int t = __shfl_up(s, d, 64);
            if (lane >= d) s += t;
        }
        if (lane == 63) wsum[wid] = s;
        __syncthreads();
        if (wid == 0) {
            int wv = (lane < 16) ? wsum[lane] : 0;
            #pragma unroll
            for (int d = 1; d < 16; d <<= 1) {
                int t = __shfl_up(wv, d, 64);
                if (lane >= d) wv += t;
            }
            if (lane < 16) wsum[lane] = wv;
        }
        __syncthreads();
        int prev = (wid > 0) ? wsum[wid - 1] : 0;
        int inc = carry_s + prev + s;
        if (i < n) off[i + 1] = inc;
        int chunk_total = wsum[15];
        __syncthreads();
        if (tid == 0) carry_s += chunk_total;
        __syncthreads();
    }
}

// ---------------- merged: weight prep + att folds + degree count -------------

__global__ __launch_bounds__(256) void wprep_kernel(
    const float* __restrict__ W0, const float* __restrict__ lw0,
    const float* __restrict__ W1, const float* __restrict__ lw1,
    const float* __restrict__ W2, const float* __restrict__ lw2,
    ushort* __restrict__ B0h, ushort* __restrict__ B0l,
    ushort* __restrict__ B1h, ushort* __restrict__ B1l,
    ushort* __restrict__ B2h, ushort* __restrict__ B2l,
    const float* __restrict__ as0, const float* __restrict__ ad0,
    const float* __restrict__ as1, const float* __restrict__ ad1,
    const float* __restrict__ as2, const float* __restrict__ ad2,
    float* __restrict__ vsd0, float* __restrict__ vsd1, float* __restrict__ vsd2,
    const int* __restrict__ edst, int* __restrict__ deg, int E)
{
    int bid = blockIdx.x, tid = threadIdx.x;
    if (bid < 1664) {
        const float* src; ushort* dh; ushort* dl; int Ncols, roff, base;
        if (bid < 256)       { src = W0;  dh = B0h; dl = B0l; Ncols = 256; roff = 0;   base = 0; }
        else if (bid < 512)  { src = lw0; dh = B0h; dl = B0l; Ncols = 256; roff = 256; base = 256; }
        else if (bid < 768)  { src = W1;  dh = B1h; dl = B1l; Ncols = 256; roff = 0;   base = 512; }
        else if (bid < 1024) { src = lw1; dh = B1h; dl = B1l; Ncols = 256; roff = 256; base = 768; }
        else if (bid < 1536) { src = W2;  dh = B2h; dl = B2l; Ncols = 512; roff = 0;   base = 1024; }
        else                 { src = lw2; dh = B2h; dl = B2l; Ncols = 128; roff = 512; base = 1536; }
        int idx = (bid - base) * 256 + tid;
        int k = idx / Ncols, n = idx - k * Ncols;
        float v = src[idx];
        unsigned short hi = bf16_rn(v);
        unsigned short lo = bf16_rn(v - bf16_tof(hi));
        int row = n + roff;
        int poff = ((row >> 4) * 8 + (k >> 5)) * 512 + (((row & 15) + 16 * ((k & 31) >> 3)) << 3) + (k & 7);
        dh[poff] = hi;
        dl[poff] = lo;
    } else if (bid < 1676) {
        int fj = (bid - 1664) >> 2;
        int idx = ((bid - 1664) & 3) * 256 + tid;   // 0..1023 = K*H
        const float *W, *as_, *ad_; float* vsd; int C;
        if (fj == 0)      { W = W0; as_ = as0; ad_ = ad0; vsd = vsd0; C = 64; }
        else if (fj == 1) { W = W1; as_ = as1; ad_ = ad1; vsd = vsd1; C = 64; }
        else              { W = W2; as_ = as2; ad_ = ad2; vsd = vsd2; C = 128; }
        int k = idx >> 2, hh = idx & 3;
        const float* wp = W + (size_t)k * (4 * C) + hh * C;
        float s = 0.f, d = 0.f;
        for (int c = 0; c < C; c++) {
            float w = wp[c];
            s += w * as_[hh * C + c];
            d += w * ad_[hh * C + c];
        }
        vsd[k * 8 + hh] = s;       // vsd layout: [k][8] = 4 src then 4 dst
        vsd[k * 8 + 4 + hh] = d;
    } else {
        int e = (bid - 1676) * 256 + tid;
        if (e < E) atomicAdd(&deg[edst[e]], 1);
    }
}

// ---------------- merged: scatter + (x -> packed bf16 + layer-0 dots) --------
// Blocks [0, egrid): CSR scatter. Blocks [egrid, ...): split_att, two nodes
// per wave (32 lanes/node, 8 floats/lane), 5-round xor-tree, ushort8 stores.

__global__ __launch_bounds__(256, 6) void scatter_split_kernel(
    const int* __restrict__ esrc, const int* __restrict__ edst,
    const int* __restrict__ off, int* __restrict__ cursor,
    int* __restrict__ csrc, int E, int egrid,
    const float* __restrict__ x, const float* __restrict__ vsd,
    ushort* __restrict__ Aph, ushort* __restrict__ Apl,
    float* __restrict__ asrc, float* __restrict__ adst, int n)
{
    int bid = blockIdx.x;
    if (bid < egrid) {
        int e = bid * 256 + threadIdx.x;
        if (e < E) {
            int d = edst[e];
            int p = off[d] + atomicAdd(&cursor[d], 1);
            csrc[p] = esrc[e];
        }
        return;
    }
    int sb = bid - egrid;
    int wid = threadIdx.x >> 6, lane = threadIdx.x & 63;
    int half = lane >> 5, sl = lane & 31;
    int d = sb * 8 + wid * 2 + half;
    if (d >= n) return;
    int k0 = sl * 8;
    float4 va = *(const float4*)(x + (size_t)d * 256 + k0);
    float4 vb = *(const float4*)(x + (size_t)d * 256 + k0 + 4);
    float v[8] = {va.x, va.y, va.z, va.w, vb.x, vb.y, vb.z, vb.w};

    ushortx8 hi, lo;
    #pragma unroll
    for (int j = 0; j < 8; ++j) {
        unsigned short h8 = bf16_rn(v[j]);
        hi[j] = h8;
        lo[j] = bf16_rn(v[j] - bf16_tof(h8));
    }
    int poff = ((d >> 4) * 8 + (k0 >> 5)) * 512 + (((d & 15) + 16 * ((k0 & 31) >> 3)) << 3);
    *(ushortx8*)(Aph + poff) = hi;
    *(ushortx8*)(Apl + poff) = lo;

    // attention dots: pa/pb[h] = sum_k v[k] * vsd[k][h] (+4 for dst)
    const float* vp = vsd + (size_t)k0 * 8;
    float pa[4] = {0.f, 0.f, 0.f, 0.f}, pb[4] = {0.f, 0.f, 0.f, 0.f};
    #pragma unroll
    for (int r = 0; r < 8; ++r) {
        float4 ra = *(const float4*)(vp + r * 8);
        float4 rb = *(const float4*)(vp + r * 8 + 4);
        pa[0] += v[r] * ra.x; pa[1] += v[r] * ra.y;
        pa[2] += v[r] * ra.z; pa[3] += v[r] * ra.w;
        pb[0] += v[r] * rb.x; pb[1] += v[r] * rb.y;
        pb[2] += v[r] * rb.z; pb[3] += v[r] * rb.w;
    }
    #pragma unroll
    for (int o = 1; o < 32; o <<= 1) {
        #pragma unroll
        for (int j = 0; j < 4; ++j) {
            pa[j] += __shfl_xor(pa[j], o, 64);
            pb[j] += __shfl_xor(pb[j], o, 64);
        }
    }
    if (sl == 0) {
        *(float4*)(asrc + (size_t)d * 4) = make_float4(pa[0], pa[1], pa[2], pa[3]);
        *(float4*)(adst + (size_t)d * 4) = make_float4(pb[0], pb[1], pb[2], pb[3]);
    }
}

// per-head global max of asrc (order-preserving uint encoding)
__global__ __launch_bounds__(256) void amax_kernel(const float* __restrict__ asrc,
                                                   unsigned int* __restrict__ amax, int n) {
    int tid = threadIdx.x;
    float4 m4 = make_float4(-1e30f, -1e30f, -1e30f, -1e30f);
    for (int i = blockIdx.x * 256 + tid; i < n; i += gridDim.x * 256) {
        float4 v = ((const float4*)asrc)[i];
        m4.x = fmaxf(m4.x, v.x); m4.y = fmaxf(m4.y, v.y);
        m4.z = fmaxf(m4.z, v.z); m4.w = fmaxf(m4.w, v.w);
    }
    #pragma unroll
    for (int o = 32; o > 0; o >>= 1) {
        m4.x = fmaxf(m4.x, __shfl_down(m4.x, o, 64));
        m4.y = fmaxf(m4.y, __shfl_down(m4.y, o, 64));
        m4.z = fmaxf(m4.z, __shfl_down(m4.z, o, 64));
        m4.w = fmaxf(m4.w, __shfl_down(m4.w, o, 64));
    }
    __shared__ float sm[4][4];
    int wid = tid >> 6, lane = tid & 63;
    if (lane == 0) { sm[wid][0] = m4.x; sm[wid][1] = m4.y; sm[wid][2] = m4.z; sm[wid][3] = m4.w; }
    __syncthreads();
    if (tid < 4) {
        float v = fmaxf(fmaxf(sm[0][tid], sm[1][tid]), fmaxf(sm[2][tid], sm[3][tid]));
        unsigned int u = __float_as_uint(v);
        u = (u >> 31) ? ~u : (u | 0x80000000u);
        atomicMax(&amax[tid], u);
    }
}

// ---------------- LDS MFMA GEMM on packed operands (m97 structure) -----------
// BM=BN=128, 4 waves (64x64 each), K=256 in 8 chunks of 32.
// Per chunk 32KB LDS: [A-hi 8K | A-lo 8K | B-hi 8K | B-lo 8K], double-buffered
// (64KB). Wave w stages region w: 8 x 1KB gload_lds16 per chunk.

__global__ __launch_bounds__(256, 2) void gemm_mfma_kernel(
    const ushort* __restrict__ Aph, const ushort* __restrict__ Apl,
    const ushort* __restrict__ Bph, const ushort* __restrict__ Bpl,
    ushort* __restrict__ O1, int n1, ushort* __restrict__ O2,
    const float* __restrict__ bias2,
    int gm, int M, int N)
{
    __shared__ __align__(16) char smem[65536];   // 2 buffers x 32KB
    int gy = N >> 7;
    int bid = blockIdx.x;
    int k8 = bid & 7, sb = bid >> 3;
    int ny = sb % gy, bxi = sb / gy;
    int bx = bxi * 8 + k8;
    if (bx >= gm) return;
    int bm = bx * 128, bn = ny * 128;

    int tid = threadIdx.x, lane = tid & 63, wv = tid >> 6;
    int wm = (wv >> 1) * 64, wn = (wv & 1) * 64;
    int fr = lane & 15, q = lane >> 4;

    // staging role: wave 0 -> A-hi, 1 -> A-lo, 2 -> B-hi, 3 -> B-lo
    const ushort* sp;
    size_t gbase;
    if (wv == 0)      { sp = Aph; gbase = (size_t)(bm >> 4) * 4096; }
    else if (wv == 1) { sp = Apl; gbase = (size_t)(bm >> 4) * 4096; }
    else if (wv == 2) { sp = Bph; gbase = (size_t)(bn >> 4) * 4096; }
    else              { sp = Bpl; gbase = (size_t)(bn >> 4) * 4096; }
    size_t gsrc = gbase + (size_t)lane * 8;   // ushort offset; 16B per lane
    int lbase = wv * 8192;                    // byte offset of this wave's region

    int agl = (wv >> 1) * 4;   // A group base for reads (= wm/16)
    int bgl = (wv & 1) * 4;    // B group base for reads (= wn/16)

    floatx4 acc[4][4] = {};

    // prologue: stage chunk 0 into buffer 0 (8 x 1KB per wave)
    #pragma unroll
    for (int t = 0; t < 8; ++t)
        gload_lds16(sp + gsrc + (size_t)t * 4096, smem + lbase + t * 1024);
    __syncthreads();

    #pragma unroll
    for (int it = 0; it < 8; ++it) {
        int cur = (it & 1) << 15;   // 0 / 32768
        if (it < 7) {
            int nb = ((it + 1) & 1) << 15;
            size_t co = gsrc + (size_t)(it + 1) * 512;
            #pragma unroll
            for (int t = 0; t < 8; ++t)
                gload_lds16(sp + co + (size_t)t * 4096, smem + nb + lbase + t * 1024);
        }
        bf16x8 cah[4], cal[4], cbh[4], cbl[4];
        #pragma unroll
        for (int i = 0; i < 4; ++i) {
            cah[i] = *(const bf16x8*)(smem + cur + (agl + i) * 1024 + lane * 16);
            cal[i] = *(const bf16x8*)(smem + cur + 8192 + (agl + i) * 1024 + lane * 16);
            cbh[i] = *(const bf16x8*)(smem + cur + 16384 + (bgl + i) * 1024 + lane * 16);
            cbl[i] = *(const bf16x8*)(smem + cur + 24576 + (bgl + i) * 1024 + lane * 16);
        }
        #pragma unroll
        for (int i = 0; i < 4; ++i)
            #pragma unroll
            for (int j = 0; j < 4; ++j) {
                acc[i][j] = __builtin_amdgcn_mfma_f32_16x16x32_bf16(cah[i], cbh[j], acc[i][j], 0, 0, 0);
                acc[i][j] = __builtin_amdgcn_mfma_f32_16x16x32_bf16(cah[i], cbl[j], acc[i][j], 0, 0, 0);
                acc[i][j] = __builtin_amdgcn_mfma_f32_16x16x32_bf16(cal[i], cbh[j], acc[i][j], 0, 0, 0);
            }
        if (it < 7) __syncthreads();
    }

    // ---- C store (C/D layout: col=lane&15, row=(lane>>4)*4+reg) ----
    int n2 = N - n1;
    #pragma unroll
    for (int i = 0; i < 4; ++i) {
        #pragma unroll
        for (int r = 0; r < 4; ++r) {
            int grow = bm + wm + i * 16 + q * 4 + r;
            if (grow < M) {
                #pragma unroll
                for (int j = 0; j < 4; ++j) {
                    int gcol = bn + wn + j * 16 + fr;
                    float v = acc[i][j][r];
                    if (gcol < n1) {
                        O1[(size_t)grow * n1 + gcol] = bf16_rn(v);
                    } else {
                        v += bias2[gcol - n1];
                        O2[(size_t)grow * n2 + (gcol - n1)] = bf16_rn(v);
                    }
                }
            }
        }
    }
}

// ---------------- aggregation layers 0/1: TWO nodes per wave -----------------
// 32 lanes per node, 8 cols/lane (ushort8 16B row loads). R18: predicated
// full-batch loop — ceil(deg/4) batches; masked slots reuse edge s1-1 (L1
// hit) with w forced to 0. No serial tail. No barriers / no LDS.

__global__ __launch_bounds__(256, 6) void agg01_kernel(
    const ushort* __restrict__ h,    // [N,256] bf16
    const float* __restrict__ asrc, const float* __restrict__ adst,
    const unsigned int* __restrict__ amax,
    const int* __restrict__ off, const int* __restrict__ csrc,
    const ushort* __restrict__ lin,  // [N,256] bf16 (lb applied in GEMM)
    const float* __restrict__ bias,  // [256]
    ushort* __restrict__ Aph, ushort* __restrict__ Apl,   // packed act out
    const float* __restrict__ vsd_next,                   // [256][8]
    float* __restrict__ asrc_out, float* __restrict__ adst_out,
    int n)
{
    int wid = threadIdx.x >> 6, lane = threadIdx.x & 63;
    int half = lane >> 5, sl = lane & 31;
    int d = blockIdx.x * 8 + wid * 2 + half;
    bool valid = (d < n);
    int dd = valid ? d : (n - 1);
    int head = sl >> 3;          // 8 lanes per head; head = c0>>6
    int c0 = sl * 8;             // 8 cols per lane
    float a_d = adst[dd * 4 + head];
    float mh = amax_decode(amax[head]) + a_d;
    float m = (mh > 0.f) ? mh : 0.2f * mh;   // >= true segment max
    int s0 = off[dd], s1 = valid ? off[dd + 1] : s0;
    int s1e = s1 - 1;

    float denom = 0.f;
    float ac[8] = {0.f, 0.f, 0.f, 0.f, 0.f, 0.f, 0.f, 0.f};
    for (int i = s0; i < s1; i += 4) {
        int i1 = (i + 1 < s1) ? i + 1 : s1e;
        int i2 = (i + 2 < s1) ? i + 2 : s1e;
        int i3 = (i + 3 < s1) ? i + 3 : s1e;
        int sa = csrc[i], sb = csrc[i1], sc = csrc[i2], sd = csrc[i3];
        float ea = asrc[sa * 4 + head];
        float eb = asrc[sb * 4 + head];
        float ec = asrc[sc * 4 + head];
        float ed = asrc[sd * 4 + head];
        ushortx8 hva = *(const ushortx8*)(h + (size_t)sa * 256 + c0);
        ushortx8 hvb = *(const ushortx8*)(h + (size_t)sb * 256 + c0);
        ushortx8 hvc = *(const ushortx8*)(h + (size_t)sc * 256 + c0);
        ushortx8 hvd = *(const ushortx8*)(h + (size_t)sd * 256 + c0);
        ea += a_d; ea = (ea > 0.f) ? ea : 0.2f * ea; float wa = __expf(ea - m);
        eb += a_d; eb = (eb > 0.f) ? eb : 0.2f * eb; float wb = __expf(eb - m);
        ec += a_d; ec = (ec > 0.f) ? ec : 0.2f * ec; float wc = __expf(ec - m);
        ed += a_d; ed = (ed > 0.f) ? ed : 0.2f * ed; float wd = __expf(ed - m);
        wb = (i + 1 < s1) ? wb : 0.f;
        wc = (i + 2 < s1) ? wc : 0.f;
        wd = (i + 3 < s1) ? wd : 0.f;
        denom += wa;
        #pragma unroll
        for (int j = 0; j < 8; ++j) ac[j] += wa * bf16_tof(hva[j]);
        denom += wb;
        #pragma unroll
        for (int j = 0; j < 8; ++j) ac[j] += wb * bf16_tof(hvb[j]);
        denom += wc;
        #pragma unroll
        for (int j = 0; j < 8; ++j) ac[j] += wc * bf16_tof(hvc[j]);
        denom += wd;
        #pragma unroll
        for (int j = 0; j < 8; ++j) ac[j] += wd * bf16_tof(hvd[j]);
    }

    if (valid) {
        float inv = 1.f / (denom + 1e-16f);
        float4 b4a = *(const float4*)(bias + c0);
        float4 b4b = *(const float4*)(bias + c0 + 4);
        ushortx8 l8 = *(const ushortx8*)(lin + (size_t)dd * 256 + c0);
        float v[8];
        v[0] = ac[0] * inv + b4a.x + bf16_tof(l8[0]);
        v[1] = ac[1] * inv + b4a.y + bf16_tof(l8[1]);
        v[2] = ac[2] * inv + b4a.z + bf16_tof(l8[2]);
        v[3] = ac[3] * inv + b4a.w + bf16_tof(l8[3]);
        v[4] = ac[4] * inv + b4b.x + bf16_tof(l8[4]);
        v[5] = ac[5] * inv + b4b.y + bf16_tof(l8[5]);
        v[6] = ac[6] * inv + b4b.z + bf16_tof(l8[6]);
        v[7] = ac[7] * inv + b4b.w + bf16_tof(l8[7]);
        #pragma unroll
        for (int j = 0; j < 8; ++j)
            v[j] = (v[j] > 0.f) ? v[j] : (__expf(v[j]) - 1.f);   // ELU

        // packed act write (8 consecutive k in one 16B store)
        ushortx8 oh, ol;
        #pragma unroll
        for (int j = 0; j < 8; ++j) {
            unsigned short hi = bf16_rn(v[j]);
            oh[j] = hi;
            ol[j] = bf16_rn(v[j] - bf16_tof(hi));
        }
        int poff = ((dd >> 4) * 8 + (c0 >> 5)) * 512 + (((dd & 15) + 16 * ((c0 & 31) >> 3)) << 3);
        *(ushortx8*)(Aph + poff) = oh;
        *(ushortx8*)(Apl + poff) = ol;

        // fused next-layer attention dots (act-derived, exact fp32 values)
        const float* vp = vsd_next + (size_t)c0 * 8;
        float pa[4] = {0.f, 0.f, 0.f, 0.f}, pb[4] = {0.f, 0.f, 0.f, 0.f};
        #pragma unroll
        for (int r = 0; r < 8; ++r) {
            float4 ra = *(const float4*)(vp + r * 8);
            float4 rb = *(const float4*)(vp + r * 8 + 4);
            pa[0] += v[r] * ra.x; pa[1] += v[r] * ra.y;
            pa[2] += v[r] * ra.z; pa[3] += v[r] * ra.w;
            pb[0] += v[r] * rb.x; pb[1] += v[r] * rb.y;
            pb[2] += v[r] * rb.z; pb[3] += v[r] * rb.w;
        }
        #pragma unroll
        for (int o = 1; o < 32; o <<= 1) {
            #pragma unroll
            for (int j = 0; j < 4; ++j) {
                pa[j] += __shfl_xor(pa[j], o, 64);
                pb[j] += __shfl_xor(pb[j], o, 64);
            }
        }
        if (sl == 0) {
            *(float4*)(asrc_out + (size_t)dd * 4) = make_float4(pa[0], pa[1], pa[2], pa[3]);
            *(float4*)(adst_out + (size_t)dd * 4) = make_float4(pb[0], pb[1], pb[2], pb[3]);
        }
    }
}

// ---------------- aggregation layer 2: wave-per-node, mean heads -------------
// R18: predicated full-batch loop (same pattern as agg01).

__global__ __launch_bounds__(256, 6) void agg2_kernel(
    const ushort* __restrict__ h,    // [N,512] bf16
    const float* __restrict__ asrc, const float* __restrict__ adst,
    const unsigned int* __restrict__ amax,
    const int* __restrict__ off, const int* __restrict__ csrc,
    const ushort* __restrict__ lin,  // [N,128] bf16 (lb2 applied in GEMM)
    const float* __restrict__ bias,  // [128]
    float* __restrict__ out,         // [N,128]
    int n)
{
    int wid = threadIdx.x >> 6, lane = threadIdx.x & 63;
    int d = blockIdx.x * 4 + wid;
    if (d >= n) return;
    int ha = lane >> 5;
    int hb = ha + 2;
    int c0 = lane * 4;
    float ad_a = adst[d * 4 + ha];
    float ad_b = adst[d * 4 + hb];
    float mha = amax_decode(amax[ha]) + ad_a;
    float mhb = amax_decode(amax[hb]) + ad_b;
    float ma = (mha > 0.f) ? mha : 0.2f * mha;
    float mb = (mhb > 0.f) ? mhb : 0.2f * mhb;
    int s0 = off[d], s1 = off[d + 1];
    int s1e = s1 - 1;

    float da = 0.f, db = 0.f;
    floatx4 aa = {0.f, 0.f, 0.f, 0.f}, ab = {0.f, 0.f, 0.f, 0.f};
    for (int i = s0; i < s1; i += 4) {
        int i1 = (i + 1 < s1) ? i + 1 : s1e;
        int i2 = (i + 2 < s1) ? i + 2 : s1e;
        int i3 = (i + 3 < s1) ? i + 3 : s1e;
        int sw = csrc[i], sx = csrc[i1], sy = csrc[i2], sz = csrc[i3];
        float ea0 = asrc[sw * 4 + ha], eb0 = asrc[sw * 4 + hb];
        float ea1 = asrc[sx * 4 + ha], eb1 = asrc[sx * 4 + hb];
        float ea2 = asrc[sy * 4 + ha], eb2 = asrc[sy * 4 + hb];
        float ea3 = asrc[sz * 4 + ha], eb3 = asrc[sz * 4 + hb];
        ushort4 va0 = *(const ushort4*)(h + (size_t)sw * 512 + c0);
        ushort4 vb0 = *(const ushort4*)(h + (size_t)sw * 512 + 256 + c0);
        ushort4 va1 = *(const ushort4*)(h + (size_t)sx * 512 + c0);
        ushort4 vb1 = *(const ushort4*)(h + (size_t)sx * 512 + 256 + c0);
        ushort4 va2 = *(const ushort4*)(h + (size_t)sy * 512 + c0);
        ushort4 vb2 = *(const ushort4*)(h + (size_t)sy * 512 + 256 + c0);
        ushort4 va3 = *(const ushort4*)(h + (size_t)sz * 512 + c0);
        ushort4 vb3 = *(const ushort4*)(h + (size_t)sz * 512 + 256 + c0);
        ea0 += ad_a; ea0 = (ea0 > 0.f) ? ea0 : 0.2f * ea0; float wa0 = __expf(ea0 - ma);
        eb0 += ad_b; eb0 = (eb0 > 0.f) ? eb0 : 0.2f * eb0; float wb0 = __expf(eb0 - mb);
        ea1 += ad_a; ea1 = (ea1 > 0.f) ? ea1 : 0.2f * ea1; float wa1 = __expf(ea1 - ma);
        eb1 += ad_b; eb1 = (eb1 > 0.f) ? eb1 : 0.2f * eb1; float wb1 = __expf(eb1 - mb);
        ea2 += ad_a; ea2 = (ea2 > 0.f) ? ea2 : 0.2f * ea2; float wa2 = __expf(ea2 - ma);
        eb2 += ad_b; eb2 = (eb2 > 0.f) ? eb2 : 0.2f * eb2; float wb2 = __expf(eb2 - mb);
        ea3 += ad_a; ea3 = (ea3 > 0.f) ? ea3 : 0.2f * ea3; float wa3 = __expf(ea3 - ma);
        eb3 += ad_b; eb3 = (eb3 > 0.f) ? eb3 : 0.2f * eb3; float wb3 = __expf(eb3 - mb);
        wa1 = (i + 1 < s1) ? wa1 : 0.f;  wb1 = (i + 1 < s1) ? wb1 : 0.f;
        wa2 = (i + 2 < s1) ? wa2 : 0.f;  wb2 = (i + 2 < s1) ? wb2 : 0.f;
        wa3 = (i + 3 < s1) ? wa3 : 0.f;  wb3 = (i + 3 < s1) ? wb3 : 0.f;
        da += wa0; db += wb0;
        aa[0] += wa0 * bf16_tof(va0.x); aa[1] += wa0 * bf16_tof(va0.y);
        aa[2] += wa0 * bf16_tof(va0.z); aa[3] += wa0 * bf16_tof(va0.w);
        ab[0] += wb0 * bf16_tof(vb0.x); ab[1] += wb0 * bf16_tof(vb0.y);
        ab[2] += wb0 * bf16_tof(vb0.z); ab[3] += wb0 * bf16_tof(vb0.w);
        da += wa1; db += wb1;
        aa[0] += wa1 * bf16_tof(va1.x); aa[1] += wa1 * bf16_tof(va1.y);
        aa[2] += wa1 * bf16_tof(va1.z); aa[3] += wa1 * bf16_tof(va1.w);
        ab[0] += wb1 * bf16_tof(vb1.x); ab[1] += wb1 * bf16_tof(vb1.y);
        ab[2] += wb1 * bf16_tof(vb1.z); ab[3] += wb1 * bf16_tof(vb1.w);
        da += wa2; db += wb2;
        aa[0] += wa2 * bf16_tof(va2.x); aa[1] += wa2 * bf16_tof(va2.y);
        aa[2] += wa2 * bf16_tof(va2.z); aa[3] += wa2 * bf16_tof(va2.w);
        ab[0] += wb2 * bf16_tof(vb2.x); ab[1] += wb2 * bf16_tof(vb2.y);
        ab[2] += wb2 * bf16_tof(vb2.z); ab[3] += wb2 * bf16_tof(vb2.w);
        da += wa3; db += wb3;
        aa[0] += wa3 * bf16_tof(va3.x); aa[1] += wa3 * bf16_tof(va3.y);
        aa[2] += wa3 * bf16_tof(va3.z); aa[3] += wa3 * bf16_tof(va3.w);
        ab[0] += wb3 * bf16_tof(vb3.x); ab[1] += wb3 * bf16_tof(vb3.y);
        ab[2] += wb3 * bf16_tof(vb3.z); ab[3] += wb3 * bf16_tof(vb3.w);
    }
    float ia = 1.f / (da + 1e-16f), ib = 1.f / (db + 1e-16f);
    float s4[4];
    #pragma unroll
    for (int j = 0; j < 4; ++j) s4[j] = aa[j] * ia + ab[j] * ib;
    float p4[4];
    #pragma unroll
    for (int j = 0; j < 4; ++j) p4[j] = __shfl_xor(s4[j], 32, 64);
    if (lane < 32) {
        float4 b4 = *(const float4*)(bias + c0);
        ushort4 l4 = *(const ushort4*)(lin + (size_t)d * 128 + c0);
        float4 o;
        o.x = 0.25f * (s4[0] + p4[0]) + b4.x + bf16_tof(l4.x);
        o.y = 0.25f * (s4[1] + p4[1]) + b4.y + bf16_tof(l4.y);
        o.z = 0.25f * (s4[2] + p4[2]) + b4.z + bf16_tof(l4.z);
        o.w = 0.25f * (s4[3] + p4[3]) + b4.w + bf16_tof(l4.w);
        *(float4*)(out + (size_t)d * 128 + c0) = o;
    }
}

// ---------------------------------------------------------------------------

extern "C" void kernel_launch(void* const* d_in, const int* in_sizes, int n_in,
                              void* d_out, int out_size, void* d_ws, size_t ws_size,
                              hipStream_t stream)
{
    const float* x   = (const float*)d_in[0];
    const int*   ei  = (const int*)d_in[1];
    const float* W0  = (const float*)d_in[2];
    const float* as0 = (const float*)d_in[3];
    const float* ad0 = (const float*)d_in[4];
    const float* b0  = (const float*)d_in[5];
    const float* lw0 = (const float*)d_in[6];
    const float* lb0 = (const float*)d_in[7];
    const float* W1  = (const float*)d_in[8];
    const float* as1 = (const float*)d_in[9];
    const float* ad1 = (const float*)d_in[10];
    const float* b1  = (const float*)d_in[11];
    const float* lw1 = (const float*)d_in[12];
    const float* lb1 = (const float*)d_in[13];
    const float* W2  = (const float*)d_in[14];
    const float* as2 = (const float*)d_in[15];
    const float* ad2 = (const float*)d_in[16];
    const float* b2  = (const float*)d_in[17];
    const float* lw2 = (const float*)d_in[18];
    const float* lb2 = (const float*)d_in[19];
    float* out = (float*)d_out;

    const int N = in_sizes[0] / 256;
    const int E = in_sizes[1] / 2;
    const int* esrc = ei;
    const int* edst = ei + E;

    const int gm = (N + 127) / 128;          // 391
    const int gmp = ((gm + 7) / 8) * 8;      // 392 (XCD multiple)
    const size_t Agroups = (size_t)gm * 8;   // 16-row groups in padded A

    // ---- workspace layout ----
    char* p = (char*)d_ws;
    ushort* act_hi = (ushort*)p; p += Agroups * 8 * 512 * 2;   // packed, 25.6 MB
    ushort* act_lo = (ushort*)p; p += Agroups * 8 * 512 * 2;
    ushort* h      = (ushort*)p; p += (size_t)N * 512 * 2;
    ushort* lin    = (ushort*)p; p += (size_t)N * 256 * 2;
    float*  as_a   = (float*)p;  p += (size_t)N * 4 * 4;
    float*  ad_a   = (float*)p;  p += (size_t)N * 4 * 4;
    float*  as_b   = (float*)p;  p += (size_t)N * 4 * 4;
    float*  ad_b   = (float*)p;  p += (size_t)N * 4 * 4;
    ushort* B0h = (ushort*)p; p += (size_t)32 * 8 * 512 * 2;   // 512 rows packed
    ushort* B0l = (ushort*)p; p += (size_t)32 * 8 * 512 * 2;
    ushort* B1h = (ushort*)p; p += (size_t)32 * 8 * 512 * 2;
    ushort* B1l = (ushort*)p; p += (size_t)32 * 8 * 512 * 2;
    ushort* B2h = (ushort*)p; p += (size_t)40 * 8 * 512 * 2;   // 640 rows packed
    ushort* B2l = (ushort*)p; p += (size_t)40 * 8 * 512 * 2;
    float* vsd0 = (float*)p; p += 256 * 8 * 4;
    float* vsd1 = (float*)p; p += 256 * 8 * 4;
    float* vsd2 = (float*)p; p += 256 * 8 * 4;
    unsigned int* amax = (unsigned int*)p;      // 12 slots (4 per layer)
    int* deg    = (int*)(amax + 12);
    int* off    = deg + N;
    int* cursor = off + N + 1;
    int* csrc   = cursor + N;

    // ---- zero amax + deg + off + cursor in one memset ----
    hipMemsetAsync(amax, 0, sizeof(int) * (size_t)(3 * N + 13), stream);

    int egrid = (E + 255) / 256;
    int g4 = (N + 3) / 4;
    int g8 = (N + 7) / 8;

    // ---- merged: weight prep + att folds + degree count ----
    wprep_kernel<<<1676 + egrid, 256, 0, stream>>>(W0, lw0, W1, lw1, W2, lw2,
                                                   B0h, B0l, B1h, B1l, B2h, B2l,
                                                   as0, ad0, as1, ad1, as2, ad2,
                                                   vsd0, vsd1, vsd2,
                                                   edst, deg, E);
    scan_kernel<<<1, 1024, 0, stream>>>(deg, off, N);

    // ---- merged: scatter + (x -> packed + layer-0 dots) ----
    scatter_split_kernel<<<egrid + g8, 256, 0, stream>>>(esrc, edst, off, cursor, csrc, E, egrid,
                                                         x, vsd0, act_hi, act_lo, as_a, ad_a, N);
    amax_kernel<<<32, 256, 0, stream>>>(as_a, amax + 0, N);

    // ---- layer 0 ----
    gemm_mfma_kernel<<<gmp * 4, 256, 0, stream>>>(act_hi, act_lo, B0h, B0l, h, 256, lin, lb0, gm, N, 512);
    agg01_kernel<<<g8, 256, 0, stream>>>(h, as_a, ad_a, amax + 0, off, csrc, lin, b0,
                                         act_hi, act_lo, vsd1, as_b, ad_b, N);
    amax_kernel<<<32, 256, 0, stream>>>(as_b, amax + 4, N);

    // ---- layer 1 ----
    gemm_mfma_kernel<<<gmp * 4, 256, 0, stream>>>(act_hi, act_lo, B1h, B1l, h, 256, lin, lb1, gm, N, 512);
    agg01_kernel<<<g8, 256, 0, stream>>>(h, as_b, ad_b, amax + 4, off, csrc, lin, b1,
                                         act_hi, act_lo, vsd2, as_a, ad_a, N);
    amax_kernel<<<32, 256, 0, stream>>>(as_a, amax + 8, N);

    // ---- layer 2 ----
    gemm_mfma_kernel<<<gmp * 5, 256, 0, stream>>>(act_hi, act_lo, B2h, B2l, h, 512, lin, lb2, gm, N, 640);
    agg2_kernel<<<g4, 256, 0, stream>>>(h, as_a, ad_a, amax + 8, off, csrc, lin, b2, out, N);
}

// Round 11
// 641.354 us; speedup vs baseline: 1.7849x; 1.0580x over previous
//
#include <hip/hip_runtime.h>
#include <cstddef>

// ---------------------------------------------------------------------------
// GAT 3-layer pipeline, round 19.
// R19: GEMM sub-phase split — each K-chunk processed as two 16KB LDS phases:
//   H: [Ah|Bh] staged, 16 hi*hi MFMA, cah/cbh HELD in registers;
//   L: [Al|Bl] staged, 32 cross MFMA (cah*cbl + cal*cbh).
//   LDS 64KB -> 32KB  => 2 -> up to 5 blocks/CU (wave-level overlap hides the
//   per-barrier vmcnt drain; R15/R18 sat at 21% MfmaUtil, 14% occupancy).
//   Per-acc MFMA order hh,hl,lh per chunk preserved -> bit-identical.
// R18 base: predicated agg01/agg2 edge loops; grid merges; amax separate.
// Packed layout (per matrix, rows padded to 128): group g=row>>4, chunk
// c=k>>5, lane l=(row&15)+16*((k&31)>>3), sub=k&7:
//   offset = (g*8+c)*512 + l*8 + sub   (ushorts)
// ---------------------------------------------------------------------------

typedef __bf16 bf16x8 __attribute__((ext_vector_type(8)));
typedef float floatx4 __attribute__((ext_vector_type(4)));
typedef unsigned short ushortx8 __attribute__((ext_vector_type(8)));

__device__ __forceinline__ unsigned short bf16_rn(float f) {
    unsigned int u = __float_as_uint(f);
    u += 0x7FFF + ((u >> 16) & 1);
    return (unsigned short)(u >> 16);
}
__device__ __forceinline__ float bf16_tof(unsigned short h) {
    return __uint_as_float(((unsigned int)h) << 16);
}

__device__ __forceinline__ float amax_decode(unsigned int u) {
    unsigned int bits = (u >> 31) ? (u & 0x7FFFFFFFu) : ~u;
    return __uint_as_float(bits);
}

// 16B-per-lane direct global->LDS copy: lds dest = base + lane*16 (HW rule).
__device__ __forceinline__ void gload_lds16(const void* g, void* l) {
    __builtin_amdgcn_global_load_lds(
        (const __attribute__((address_space(1))) unsigned int*)g,
        (__attribute__((address_space(3))) unsigned int*)l, 16, 0, 0);
}

// ---------------- CSR scan (single block) ----------------

__global__ __launch_bounds__(1024) void scan_kernel(const int* __restrict__ deg,
                                                    int* __restrict__ off, int n) {
    __shared__ int wsum[16];
    __shared__ int carry_s;
    int tid = threadIdx.x, lane = tid & 63, wid = tid >> 6;
    if (tid == 0) { carry_s = 0; off[0] = 0; }
    __syncthreads();
    for (int base = 0; base < n; base += 1024) {
        int i = base + tid;
        int v = (i < n) ? deg[i] : 0;
        int s = v;
        #pragma unroll
        for (int d = 1; d < 64; d <<= 1) {
            int t = __shfl_up(s, d, 64);
            if (lane >= d) s += t;
        }
        if (lane == 63) wsum[wid] = s;
        __syncthreads();
        if (wid == 0) {
            int wv = (lane < 16) ? wsum[lane] : 0;
            #pragma unroll
            for (int d = 1; d < 16; d <<= 1) {
                int t = __shfl_up(wv, d, 64);
                if (lane >= d) wv += t;
            }
            if (lane < 16) wsum[lane] = wv;
        }
        __syncthreads();
        int prev = (wid > 0) ? wsum[wid - 1] : 0;
        int inc = carry_s + prev + s;
        if (i < n) off[i + 1] = inc;
        int chunk_total = wsum[15];
        __syncthreads();
        if (tid == 0) carry_s += chunk_total;
        __syncthreads();
    }
}

// ---------------- merged: weight prep + att folds + degree count -------------

__global__ __launch_bounds__(256) void wprep_kernel(
    const float* __restrict__ W0, const float* __restrict__ lw0,
    const float* __restrict__ W1, const float* __restrict__ lw1,
    const float* __restrict__ W2, const float* __restrict__ lw2,
    ushort* __restrict__ B0h, ushort* __restrict__ B0l,
    ushort* __restrict__ B1h, ushort* __restrict__ B1l,
    ushort* __restrict__ B2h, ushort* __restrict__ B2l,
    const float* __restrict__ as0, const float* __restrict__ ad0,
    const float* __restrict__ as1, const float* __restrict__ ad1,
    const float* __restrict__ as2, const float* __restrict__ ad2,
    float* __restrict__ vsd0, float* __restrict__ vsd1, float* __restrict__ vsd2,
    const int* __restrict__ edst, int* __restrict__ deg, int E)
{
    int bid = blockIdx.x, tid = threadIdx.x;
    if (bid < 1664) {
        const float* src; ushort* dh; ushort* dl; int Ncols, roff, base;
        if (bid < 256)       { src = W0;  dh = B0h; dl = B0l; Ncols = 256; roff = 0;   base = 0; }
        else if (bid < 512)  { src = lw0; dh = B0h; dl = B0l; Ncols = 256; roff = 256; base = 256; }
        else if (bid < 768)  { src = W1;  dh = B1h; dl = B1l; Ncols = 256; roff = 0;   base = 512; }
        else if (bid < 1024) { src = lw1; dh = B1h; dl = B1l; Ncols = 256; roff = 256; base = 768; }
        else if (bid < 1536) { src = W2;  dh = B2h; dl = B2l; Ncols = 512; roff = 0;   base = 1024; }
        else                 { src = lw2; dh = B2h; dl = B2l; Ncols = 128; roff = 512; base = 1536; }
        int idx = (bid - base) * 256 + tid;
        int k = idx / Ncols, n = idx - k * Ncols;
        float v = src[idx];
        unsigned short hi = bf16_rn(v);
        unsigned short lo = bf16_rn(v - bf16_tof(hi));
        int row = n + roff;
        int poff = ((row >> 4) * 8 + (k >> 5)) * 512 + (((row & 15) + 16 * ((k & 31) >> 3)) << 3) + (k & 7);
        dh[poff] = hi;
        dl[poff] = lo;
    } else if (bid < 1676) {
        int fj = (bid - 1664) >> 2;
        int idx = ((bid - 1664) & 3) * 256 + tid;   // 0..1023 = K*H
        const float *W, *as_, *ad_; float* vsd; int C;
        if (fj == 0)      { W = W0; as_ = as0; ad_ = ad0; vsd = vsd0; C = 64; }
        else if (fj == 1) { W = W1; as_ = as1; ad_ = ad1; vsd = vsd1; C = 64; }
        else              { W = W2; as_ = as2; ad_ = ad2; vsd = vsd2; C = 128; }
        int k = idx >> 2, hh = idx & 3;
        const float* wp = W + (size_t)k * (4 * C) + hh * C;
        float s = 0.f, d = 0.f;
        for (int c = 0; c < C; c++) {
            float w = wp[c];
            s += w * as_[hh * C + c];
            d += w * ad_[hh * C + c];
        }
        vsd[k * 8 + hh] = s;       // vsd layout: [k][8] = 4 src then 4 dst
        vsd[k * 8 + 4 + hh] = d;
    } else {
        int e = (bid - 1676) * 256 + tid;
        if (e < E) atomicAdd(&deg[edst[e]], 1);
    }
}

// ---------------- merged: scatter + (x -> packed bf16 + layer-0 dots) --------
// Blocks [0, egrid): CSR scatter. Blocks [egrid, ...): split_att, two nodes
// per wave (32 lanes/node, 8 floats/lane), 5-round xor-tree, ushort8 stores.

__global__ __launch_bounds__(256, 6) void scatter_split_kernel(
    const int* __restrict__ esrc, const int* __restrict__ edst,
    const int* __restrict__ off, int* __restrict__ cursor,
    int* __restrict__ csrc, int E, int egrid,
    const float* __restrict__ x, const float* __restrict__ vsd,
    ushort* __restrict__ Aph, ushort* __restrict__ Apl,
    float* __restrict__ asrc, float* __restrict__ adst, int n)
{
    int bid = blockIdx.x;
    if (bid < egrid) {
        int e = bid * 256 + threadIdx.x;
        if (e < E) {
            int d = edst[e];
            int p = off[d] + atomicAdd(&cursor[d], 1);
            csrc[p] = esrc[e];
        }
        return;
    }
    int sb = bid - egrid;
    int wid = threadIdx.x >> 6, lane = threadIdx.x & 63;
    int half = lane >> 5, sl = lane & 31;
    int d = sb * 8 + wid * 2 + half;
    if (d >= n) return;
    int k0 = sl * 8;
    float4 va = *(const float4*)(x + (size_t)d * 256 + k0);
    float4 vb = *(const float4*)(x + (size_t)d * 256 + k0 + 4);
    float v[8] = {va.x, va.y, va.z, va.w, vb.x, vb.y, vb.z, vb.w};

    ushortx8 hi, lo;
    #pragma unroll
    for (int j = 0; j < 8; ++j) {
        unsigned short h8 = bf16_rn(v[j]);
        hi[j] = h8;
        lo[j] = bf16_rn(v[j] - bf16_tof(h8));
    }
    int poff = ((d >> 4) * 8 + (k0 >> 5)) * 512 + (((d & 15) + 16 * ((k0 & 31) >> 3)) << 3);
    *(ushortx8*)(Aph + poff) = hi;
    *(ushortx8*)(Apl + poff) = lo;

    // attention dots: pa/pb[h] = sum_k v[k] * vsd[k][h] (+4 for dst)
    const float* vp = vsd + (size_t)k0 * 8;
    float pa[4] = {0.f, 0.f, 0.f, 0.f}, pb[4] = {0.f, 0.f, 0.f, 0.f};
    #pragma unroll
    for (int r = 0; r < 8; ++r) {
        float4 ra = *(const float4*)(vp + r * 8);
        float4 rb = *(const float4*)(vp + r * 8 + 4);
        pa[0] += v[r] * ra.x; pa[1] += v[r] * ra.y;
        pa[2] += v[r] * ra.z; pa[3] += v[r] * ra.w;
        pb[0] += v[r] * rb.x; pb[1] += v[r] * rb.y;
        pb[2] += v[r] * rb.z; pb[3] += v[r] * rb.w;
    }
    #pragma unroll
    for (int o = 1; o < 32; o <<= 1) {
        #pragma unroll
        for (int j = 0; j < 4; ++j) {
            pa[j] += __shfl_xor(pa[j], o, 64);
            pb[j] += __shfl_xor(pb[j], o, 64);
        }
    }
    if (sl == 0) {
        *(float4*)(asrc + (size_t)d * 4) = make_float4(pa[0], pa[1], pa[2], pa[3]);
        *(float4*)(adst + (size_t)d * 4) = make_float4(pb[0], pb[1], pb[2], pb[3]);
    }
}

// per-head global max of asrc (order-preserving uint encoding)
__global__ __launch_bounds__(256) void amax_kernel(const float* __restrict__ asrc,
                                                   unsigned int* __restrict__ amax, int n) {
    int tid = threadIdx.x;
    float4 m4 = make_float4(-1e30f, -1e30f, -1e30f, -1e30f);
    for (int i = blockIdx.x * 256 + tid; i < n; i += gridDim.x * 256) {
        float4 v = ((const float4*)asrc)[i];
        m4.x = fmaxf(m4.x, v.x); m4.y = fmaxf(m4.y, v.y);
        m4.z = fmaxf(m4.z, v.z); m4.w = fmaxf(m4.w, v.w);
    }
    #pragma unroll
    for (int o = 32; o > 0; o >>= 1) {
        m4.x = fmaxf(m4.x, __shfl_down(m4.x, o, 64));
        m4.y = fmaxf(m4.y, __shfl_down(m4.y, o, 64));
        m4.z = fmaxf(m4.z, __shfl_down(m4.z, o, 64));
        m4.w = fmaxf(m4.w, __shfl_down(m4.w, o, 64));
    }
    __shared__ float sm[4][4];
    int wid = tid >> 6, lane = tid & 63;
    if (lane == 0) { sm[wid][0] = m4.x; sm[wid][1] = m4.y; sm[wid][2] = m4.z; sm[wid][3] = m4.w; }
    __syncthreads();
    if (tid < 4) {
        float v = fmaxf(fmaxf(sm[0][tid], sm[1][tid]), fmaxf(sm[2][tid], sm[3][tid]));
        unsigned int u = __float_as_uint(v);
        u = (u >> 31) ? ~u : (u | 0x80000000u);
        atomicMax(&amax[tid], u);
    }
}

// ---------------- LDS MFMA GEMM, sub-phase split (R19) -----------------------
// BM=BN=128, 4 waves (64x64 each), K=256 in 8 chunks of 32, each chunk as
// two phases: H=[Ah 8K|Bh 8K] (16 hi*hi MFMA; cah/cbh held in regs),
// L=[Al 8K|Bl 8K] (32 cross MFMA). LDS 2 x 16KB = 32KB -> more blocks/CU.
// Wave w stages 4KB/phase: w0=A grp0-3, w1=A grp4-7, w2=B grp0-3, w3=B grp4-7.

__global__ __launch_bounds__(256, 2) void gemm_mfma_kernel(
    const ushort* __restrict__ Aph, const ushort* __restrict__ Apl,
    const ushort* __restrict__ Bph, const ushort* __restrict__ Bpl,
    ushort* __restrict__ O1, int n1, ushort* __restrict__ O2,
    const float* __restrict__ bias2,
    int gm, int M, int N)
{
    __shared__ __align__(16) char smem[32768];   // 2 buffers x 16KB
    int gy = N >> 7;
    int bid = blockIdx.x;
    int k8 = bid & 7, sb = bid >> 3;
    int ny = sb % gy, bxi = sb / gy;
    int bx = bxi * 8 + k8;
    if (bx >= gm) return;
    int bm = bx * 128, bn = ny * 128;

    int tid = threadIdx.x, lane = tid & 63, wv = tid >> 6;
    int wm = (wv >> 1) * 64, wn = (wv & 1) * 64;
    int fr = lane & 15, q = lane >> 4;

    // staging sources for this wave (hi-phase / lo-phase)
    const ushort* sp_h = (wv < 2) ? Aph : Bph;
    const ushort* sp_l = (wv < 2) ? Apl : Bpl;
    size_t gsrc = ((size_t)((wv < 2) ? (bm >> 4) : (bn >> 4)) + (size_t)((wv & 1) * 4)) * 4096
                + (size_t)lane * 8;
    int lbase = wv * 4096;     // byte offset of this wave's 4KB region in buffer

    int agl = (wv >> 1) * 4;   // A group base for reads (= wm/16)
    int bgl = (wv & 1) * 4;    // B group base for reads (= wn/16)

    floatx4 acc[4][4] = {};
    bf16x8 cah[4], cbh[4];     // persist H -> L phase

    // prologue: stage phase 0 (hi of chunk 0) into buffer 0 (4 x 1KB per wave)
    #pragma unroll
    for (int t = 0; t < 4; ++t)
        gload_lds16(sp_h + gsrc + (size_t)t * 4096, smem + lbase + t * 1024);
    __syncthreads();

    #pragma unroll
    for (int p = 0; p < 16; ++p) {
        int cur = (p & 1) << 14;   // 0 / 16384
        // stage next phase into the other buffer (issued first)
        if (p < 15) {
            int nb = ((p + 1) & 1) << 14;
            const ushort* sp = ((p + 1) & 1) ? sp_l : sp_h;
            size_t co = gsrc + (size_t)((p + 1) >> 1) * 512;
            #pragma unroll
            for (int t = 0; t < 4; ++t)
                gload_lds16(sp + co + (size_t)t * 4096, smem + nb + lbase + t * 1024);
        }
        if (!(p & 1)) {
            // H phase: read cah/cbh (held), compute hi*hi
            #pragma unroll
            for (int i = 0; i < 4; ++i) {
                cah[i] = *(const bf16x8*)(smem + cur + (agl + i) * 1024 + lane * 16);
                cbh[i] = *(const bf16x8*)(smem + cur + 8192 + (bgl + i) * 1024 + lane * 16);
            }
            #pragma unroll
            for (int i = 0; i < 4; ++i)
                #pragma unroll
                for (int j = 0; j < 4; ++j)
                    acc[i][j] = __builtin_amdgcn_mfma_f32_16x16x32_bf16(cah[i], cbh[j], acc[i][j], 0, 0, 0);
        } else {
            // L phase: read cal/cbl, compute cross terms (order hl then lh)
            bf16x8 cal[4], cbl[4];
            #pragma unroll
            for (int i = 0; i < 4; ++i) {
                cal[i] = *(const bf16x8*)(smem + cur + (agl + i) * 1024 + lane * 16);
                cbl[i] = *(const bf16x8*)(smem + cur + 8192 + (bgl + i) * 1024 + lane * 16);
            }
            #pragma unroll
            for (int i = 0; i < 4; ++i)
                #pragma unroll
                for (int j = 0; j < 4; ++j) {
                    acc[i][j] = __builtin_amdgcn_mfma_f32_16x16x32_bf16(cah[i], cbl[j], acc[i][j], 0, 0, 0);
                    acc[i][j] = __builtin_amdgcn_mfma_f32_16x16x32_bf16(cal[i], cbh[j], acc[i][j], 0, 0, 0);
                }
        }
        if (p < 15) __syncthreads();
    }

    // ---- C store (C/D layout: col=lane&15, row=(lane>>4)*4+reg) ----
    int n2 = N - n1;
    #pragma unroll
    for (int i = 0; i < 4; ++i) {
        #pragma unroll
        for (int r = 0; r < 4; ++r) {
            int grow = bm + wm + i * 16 + q * 4 + r;
            if (grow < M) {
                #pragma unroll
                for (int j = 0; j < 4; ++j) {
                    int gcol = bn + wn + j * 16 + fr;
                    float v = acc[i][j][r];
                    if (gcol < n1) {
                        O1[(size_t)grow * n1 + gcol] = bf16_rn(v);
                    } else {
                        v += bias2[gcol - n1];
                        O2[(size_t)grow * n2 + (gcol - n1)] = bf16_rn(v);
                    }
                }
            }
        }
    }
}

// ---------------- aggregation layers 0/1: TWO nodes per wave -----------------
// 32 lanes per node, 8 cols/lane (ushort8 16B row loads). Predicated
// full-batch loop — ceil(deg/4) batches; masked slots reuse edge s1-1 (L1
// hit) with w forced to 0. No serial tail. No barriers / no LDS.

__global__ __launch_bounds__(256, 6) void agg01_kernel(
    const ushort* __restrict__ h,    // [N,256] bf16
    const float* __restrict__ asrc, const float* __restrict__ adst,
    const unsigned int* __restrict__ amax,
    const int* __restrict__ off, const int* __restrict__ csrc,
    const ushort* __restrict__ lin,  // [N,256] bf16 (lb applied in GEMM)
    const float* __restrict__ bias,  // [256]
    ushort* __restrict__ Aph, ushort* __restrict__ Apl,   // packed act out
    const float* __restrict__ vsd_next,                   // [256][8]
    float* __restrict__ asrc_out, float* __restrict__ adst_out,
    int n)
{
    int wid = threadIdx.x >> 6, lane = threadIdx.x & 63;
    int half = lane >> 5, sl = lane & 31;
    int d = blockIdx.x * 8 + wid * 2 + half;
    bool valid = (d < n);
    int dd = valid ? d : (n - 1);
    int head = sl >> 3;          // 8 lanes per head; head = c0>>6
    int c0 = sl * 8;             // 8 cols per lane
    float a_d = adst[dd * 4 + head];
    float mh = amax_decode(amax[head]) + a_d;
    float m = (mh > 0.f) ? mh : 0.2f * mh;   // >= true segment max
    int s0 = off[dd], s1 = valid ? off[dd + 1] : s0;
    int s1e = s1 - 1;

    float denom = 0.f;
    float ac[8] = {0.f, 0.f, 0.f, 0.f, 0.f, 0.f, 0.f, 0.f};
    for (int i = s0; i < s1; i += 4) {
        int i1 = (i + 1 < s1) ? i + 1 : s1e;
        int i2 = (i + 2 < s1) ? i + 2 : s1e;
        int i3 = (i + 3 < s1) ? i + 3 : s1e;
        int sa = csrc[i], sb = csrc[i1], sc = csrc[i2], sd = csrc[i3];
        float ea = asrc[sa * 4 + head];
        float eb = asrc[sb * 4 + head];
        float ec = asrc[sc * 4 + head];
        float ed = asrc[sd * 4 + head];
        ushortx8 hva = *(const ushortx8*)(h + (size_t)sa * 256 + c0);
        ushortx8 hvb = *(const ushortx8*)(h + (size_t)sb * 256 + c0);
        ushortx8 hvc = *(const ushortx8*)(h + (size_t)sc * 256 + c0);
        ushortx8 hvd = *(const ushortx8*)(h + (size_t)sd * 256 + c0);
        ea += a_d; ea = (ea > 0.f) ? ea : 0.2f * ea; float wa = __expf(ea - m);
        eb += a_d; eb = (eb > 0.f) ? eb : 0.2f * eb; float wb = __expf(eb - m);
        ec += a_d; ec = (ec > 0.f) ? ec : 0.2f * ec; float wc = __expf(ec - m);
        ed += a_d; ed = (ed > 0.f) ? ed : 0.2f * ed; float wd = __expf(ed - m);
        wb = (i + 1 < s1) ? wb : 0.f;
        wc = (i + 2 < s1) ? wc : 0.f;
        wd = (i + 3 < s1) ? wd : 0.f;
        denom += wa;
        #pragma unroll
        for (int j = 0; j < 8; ++j) ac[j] += wa * bf16_tof(hva[j]);
        denom += wb;
        #pragma unroll
        for (int j = 0; j < 8; ++j) ac[j] += wb * bf16_tof(hvb[j]);
        denom += wc;
        #pragma unroll
        for (int j = 0; j < 8; ++j) ac[j] += wc * bf16_tof(hvc[j]);
        denom += wd;
        #pragma unroll
        for (int j = 0; j < 8; ++j) ac[j] += wd * bf16_tof(hvd[j]);
    }

    if (valid) {
        float inv = 1.f / (denom + 1e-16f);
        float4 b4a = *(const float4*)(bias + c0);
        float4 b4b = *(const float4*)(bias + c0 + 4);
        ushortx8 l8 = *(const ushortx8*)(lin + (size_t)dd * 256 + c0);
        float v[8];
        v[0] = ac[0] * inv + b4a.x + bf16_tof(l8[0]);
        v[1] = ac[1] * inv + b4a.y + bf16_tof(l8[1]);
        v[2] = ac[2] * inv + b4a.z + bf16_tof(l8[2]);
        v[3] = ac[3] * inv + b4a.w + bf16_tof(l8[3]);
        v[4] = ac[4] * inv + b4b.x + bf16_tof(l8[4]);
        v[5] = ac[5] * inv + b4b.y + bf16_tof(l8[5]);
        v[6] = ac[6] * inv + b4b.z + bf16_tof(l8[6]);
        v[7] = ac[7] * inv + b4b.w + bf16_tof(l8[7]);
        #pragma unroll
        for (int j = 0; j < 8; ++j)
            v[j] = (v[j] > 0.f) ? v[j] : (__expf(v[j]) - 1.f);   // ELU

        // packed act write (8 consecutive k in one 16B store)
        ushortx8 oh, ol;
        #pragma unroll
        for (int j = 0; j < 8; ++j) {
            unsigned short hi = bf16_rn(v[j]);
            oh[j] = hi;
            ol[j] = bf16_rn(v[j] - bf16_tof(hi));
        }
        int poff = ((dd >> 4) * 8 + (c0 >> 5)) * 512 + (((dd & 15) + 16 * ((c0 & 31) >> 3)) << 3);
        *(ushortx8*)(Aph + poff) = oh;
        *(ushortx8*)(Apl + poff) = ol;

        // fused next-layer attention dots (act-derived, exact fp32 values)
        const float* vp = vsd_next + (size_t)c0 * 8;
        float pa[4] = {0.f, 0.f, 0.f, 0.f}, pb[4] = {0.f, 0.f, 0.f, 0.f};
        #pragma unroll
        for (int r = 0; r < 8; ++r) {
            float4 ra = *(const float4*)(vp + r * 8);
            float4 rb = *(const float4*)(vp + r * 8 + 4);
            pa[0] += v[r] * ra.x; pa[1] += v[r] * ra.y;
            pa[2] += v[r] * ra.z; pa[3] += v[r] * ra.w;
            pb[0] += v[r] * rb.x; pb[1] += v[r] * rb.y;
            pb[2] += v[r] * rb.z; pb[3] += v[r] * rb.w;
        }
        #pragma unroll
        for (int o = 1; o < 32; o <<= 1) {
            #pragma unroll
            for (int j = 0; j < 4; ++j) {
                pa[j] += __shfl_xor(pa[j], o, 64);
                pb[j] += __shfl_xor(pb[j], o, 64);
            }
        }
        if (sl == 0) {
            *(float4*)(asrc_out + (size_t)dd * 4) = make_float4(pa[0], pa[1], pa[2], pa[3]);
            *(float4*)(adst_out + (size_t)dd * 4) = make_float4(pb[0], pb[1], pb[2], pb[3]);
        }
    }
}

// ---------------- aggregation layer 2: wave-per-node, mean heads -------------
// Predicated full-batch loop (same pattern as agg01).

__global__ __launch_bounds__(256, 6) void agg2_kernel(
    const ushort* __restrict__ h,    // [N,512] bf16
    const float* __restrict__ asrc, const float* __restrict__ adst,
    const unsigned int* __restrict__ amax,
    const int* __restrict__ off, const int* __restrict__ csrc,
    const ushort* __restrict__ lin,  // [N,128] bf16 (lb2 applied in GEMM)
    const float* __restrict__ bias,  // [128]
    float* __restrict__ out,         // [N,128]
    int n)
{
    int wid = threadIdx.x >> 6, lane = threadIdx.x & 63;
    int d = blockIdx.x * 4 + wid;
    if (d >= n) return;
    int ha = lane >> 5;
    int hb = ha + 2;
    int c0 = lane * 4;
    float ad_a = adst[d * 4 + ha];
    float ad_b = adst[d * 4 + hb];
    float mha = amax_decode(amax[ha]) + ad_a;
    float mhb = amax_decode(amax[hb]) + ad_b;
    float ma = (mha > 0.f) ? mha : 0.2f * mha;
    float mb = (mhb > 0.f) ? mhb : 0.2f * mhb;
    int s0 = off[d], s1 = off[d + 1];
    int s1e = s1 - 1;

    float da = 0.f, db = 0.f;
    floatx4 aa = {0.f, 0.f, 0.f, 0.f}, ab = {0.f, 0.f, 0.f, 0.f};
    for (int i = s0; i < s1; i += 4) {
        int i1 = (i + 1 < s1) ? i + 1 : s1e;
        int i2 = (i + 2 < s1) ? i + 2 : s1e;
        int i3 = (i + 3 < s1) ? i + 3 : s1e;
        int sw = csrc[i], sx = csrc[i1], sy = csrc[i2], sz = csrc[i3];
        float ea0 = asrc[sw * 4 + ha], eb0 = asrc[sw * 4 + hb];
        float ea1 = asrc[sx * 4 + ha], eb1 = asrc[sx * 4 + hb];
        float ea2 = asrc[sy * 4 + ha], eb2 = asrc[sy * 4 + hb];
        float ea3 = asrc[sz * 4 + ha], eb3 = asrc[sz * 4 + hb];
        ushort4 va0 = *(const ushort4*)(h + (size_t)sw * 512 + c0);
        ushort4 vb0 = *(const ushort4*)(h + (size_t)sw * 512 + 256 + c0);
        ushort4 va1 = *(const ushort4*)(h + (size_t)sx * 512 + c0);
        ushort4 vb1 = *(const ushort4*)(h + (size_t)sx * 512 + 256 + c0);
        ushort4 va2 = *(const ushort4*)(h + (size_t)sy * 512 + c0);
        ushort4 vb2 = *(const ushort4*)(h + (size_t)sy * 512 + 256 + c0);
        ushort4 va3 = *(const ushort4*)(h + (size_t)sz * 512 + c0);
        ushort4 vb3 = *(const ushort4*)(h + (size_t)sz * 512 + 256 + c0);
        ea0 += ad_a; ea0 = (ea0 > 0.f) ? ea0 : 0.2f * ea0; float wa0 = __expf(ea0 - ma);
        eb0 += ad_b; eb0 = (eb0 > 0.f) ? eb0 : 0.2f * eb0; float wb0 = __expf(eb0 - mb);
        ea1 += ad_a; ea1 = (ea1 > 0.f) ? ea1 : 0.2f * ea1; float wa1 = __expf(ea1 - ma);
        eb1 += ad_b; eb1 = (eb1 > 0.f) ? eb1 : 0.2f * eb1; float wb1 = __expf(eb1 - mb);
        ea2 += ad_a; ea2 = (ea2 > 0.f) ? ea2 : 0.2f * ea2; float wa2 = __expf(ea2 - ma);
        eb2 += ad_b; eb2 = (eb2 > 0.f) ? eb2 : 0.2f * eb2; float wb2 = __expf(eb2 - mb);
        ea3 += ad_a; ea3 = (ea3 > 0.f) ? ea3 : 0.2f * ea3; float wa3 = __expf(ea3 - ma);
        eb3 += ad_b; eb3 = (eb3 > 0.f) ? eb3 : 0.2f * eb3; float wb3 = __expf(eb3 - mb);
        wa1 = (i + 1 < s1) ? wa1 : 0.f;  wb1 = (i + 1 < s1) ? wb1 : 0.f;
        wa2 = (i + 2 < s1) ? wa2 : 0.f;  wb2 = (i + 2 < s1) ? wb2 : 0.f;
        wa3 = (i + 3 < s1) ? wa3 : 0.f;  wb3 = (i + 3 < s1) ? wb3 : 0.f;
        da += wa0; db += wb0;
        aa[0] += wa0 * bf16_tof(va0.x); aa[1] += wa0 * bf16_tof(va0.y);
        aa[2] += wa0 * bf16_tof(va0.z); aa[3] += wa0 * bf16_tof(va0.w);
        ab[0] += wb0 * bf16_tof(vb0.x); ab[1] += wb0 * bf16_tof(vb0.y);
        ab[2] += wb0 * bf16_tof(vb0.z); ab[3] += wb0 * bf16_tof(vb0.w);
        da += wa1; db += wb1;
        aa[0] += wa1 * bf16_tof(va1.x); aa[1] += wa1 * bf16_tof(va1.y);
        aa[2] += wa1 * bf16_tof(va1.z); aa[3] += wa1 * bf16_tof(va1.w);
        ab[0] += wb1 * bf16_tof(vb1.x); ab[1] += wb1 * bf16_tof(vb1.y);
        ab[2] += wb1 * bf16_tof(vb1.z); ab[3] += wb1 * bf16_tof(vb1.w);
        da += wa2; db += wb2;
        aa[0] += wa2 * bf16_tof(va2.x); aa[1] += wa2 * bf16_tof(va2.y);
        aa[2] += wa2 * bf16_tof(va2.z); aa[3] += wa2 * bf16_tof(va2.w);
        ab[0] += wb2 * bf16_tof(vb2.x); ab[1] += wb2 * bf16_tof(vb2.y);
        ab[2] += wb2 * bf16_tof(vb2.z); ab[3] += wb2 * bf16_tof(vb2.w);
        da += wa3; db += wb3;
        aa[0] += wa3 * bf16_tof(va3.x); aa[1] += wa3 * bf16_tof(va3.y);
        aa[2] += wa3 * bf16_tof(va3.z); aa[3] += wa3 * bf16_tof(va3.w);
        ab[0] += wb3 * bf16_tof(vb3.x); ab[1] += wb3 * bf16_tof(vb3.y);
        ab[2] += wb3 * bf16_tof(vb3.z); ab[3] += wb3 * bf16_tof(vb3.w);
    }
    float ia = 1.f / (da + 1e-16f), ib = 1.f / (db + 1e-16f);
    float s4[4];
    #pragma unroll
    for (int j = 0; j < 4; ++j) s4[j] = aa[j] * ia + ab[j] * ib;
    float p4[4];
    #pragma unroll
    for (int j = 0; j < 4; ++j) p4[j] = __shfl_xor(s4[j], 32, 64);
    if (lane < 32) {
        float4 b4 = *(const float4*)(bias + c0);
        ushort4 l4 = *(const ushort4*)(lin + (size_t)d * 128 + c0);
        float4 o;
        o.x = 0.25f * (s4[0] + p4[0]) + b4.x + bf16_tof(l4.x);
        o.y = 0.25f * (s4[1] + p4[1]) + b4.y + bf16_tof(l4.y);
        o.z = 0.25f * (s4[2] + p4[2]) + b4.z + bf16_tof(l4.z);
        o.w = 0.25f * (s4[3] + p4[3]) + b4.w + bf16_tof(l4.w);
        *(float4*)(out + (size_t)d * 128 + c0) = o;
    }
}

// ---------------------------------------------------------------------------

extern "C" void kernel_launch(void* const* d_in, const int* in_sizes, int n_in,
                              void* d_out, int out_size, void* d_ws, size_t ws_size,
                              hipStream_t stream)
{
    const float* x   = (const float*)d_in[0];
    const int*   ei  = (const int*)d_in[1];
    const float* W0  = (const float*)d_in[2];
    const float* as0 = (const float*)d_in[3];
    const float* ad0 = (const float*)d_in[4];
    const float* b0  = (const float*)d_in[5];
    const float* lw0 = (const float*)d_in[6];
    const float* lb0 = (const float*)d_in[7];
    const float* W1  = (const float*)d_in[8];
    const float* as1 = (const float*)d_in[9];
    const float* ad1 = (const float*)d_in[10];
    const float* b1  = (const float*)d_in[11];
    const float* lw1 = (const float*)d_in[12];
    const float* lb1 = (const float*)d_in[13];
    const float* W2  = (const float*)d_in[14];
    const float* as2 = (const float*)d_in[15];
    const float* ad2 = (const float*)d_in[16];
    const float* b2  = (const float*)d_in[17];
    const float* lw2 = (const float*)d_in[18];
    const float* lb2 = (const float*)d_in[19];
    float* out = (float*)d_out;

    const int N = in_sizes[0] / 256;
    const int E = in_sizes[1] / 2;
    const int* esrc = ei;
    const int* edst = ei + E;

    const int gm = (N + 127) / 128;          // 391
    const int gmp = ((gm + 7) / 8) * 8;      // 392 (XCD multiple)
    const size_t Agroups = (size_t)gm * 8;   // 16-row groups in padded A

    // ---- workspace layout ----
    char* p = (char*)d_ws;
    ushort* act_hi = (ushort*)p; p += Agroups * 8 * 512 * 2;   // packed, 25.6 MB
    ushort* act_lo = (ushort*)p; p += Agroups * 8 * 512 * 2;
    ushort* h      = (ushort*)p; p += (size_t)N * 512 * 2;
    ushort* lin    = (ushort*)p; p += (size_t)N * 256 * 2;
    float*  as_a   = (float*)p;  p += (size_t)N * 4 * 4;
    float*  ad_a   = (float*)p;  p += (size_t)N * 4 * 4;
    float*  as_b   = (float*)p;  p += (size_t)N * 4 * 4;
    float*  ad_b   = (float*)p;  p += (size_t)N * 4 * 4;
    ushort* B0h = (ushort*)p; p += (size_t)32 * 8 * 512 * 2;   // 512 rows packed
    ushort* B0l = (ushort*)p; p += (size_t)32 * 8 * 512 * 2;
    ushort* B1h = (ushort*)p; p += (size_t)32 * 8 * 512 * 2;
    ushort* B1l = (ushort*)p; p += (size_t)32 * 8 * 512 * 2;
    ushort* B2h = (ushort*)p; p += (size_t)40 * 8 * 512 * 2;   // 640 rows packed
    ushort* B2l = (ushort*)p; p += (size_t)40 * 8 * 512 * 2;
    float* vsd0 = (float*)p; p += 256 * 8 * 4;
    float* vsd1 = (float*)p; p += 256 * 8 * 4;
    float* vsd2 = (float*)p; p += 256 * 8 * 4;
    unsigned int* amax = (unsigned int*)p;      // 12 slots (4 per layer)
    int* deg    = (int*)(amax + 12);
    int* off    = deg + N;
    int* cursor = off + N + 1;
    int* csrc   = cursor + N;

    // ---- zero amax + deg + off + cursor in one memset ----
    hipMemsetAsync(amax, 0, sizeof(int) * (size_t)(3 * N + 13), stream);

    int egrid = (E + 255) / 256;
    int g4 = (N + 3) / 4;
    int g8 = (N + 7) / 8;

    // ---- merged: weight prep + att folds + degree count ----
    wprep_kernel<<<1676 + egrid, 256, 0, stream>>>(W0, lw0, W1, lw1, W2, lw2,
                                                   B0h, B0l, B1h, B1l, B2h, B2l,
                                                   as0, ad0, as1, ad1, as2, ad2,
                                                   vsd0, vsd1, vsd2,
                                                   edst, deg, E);
    scan_kernel<<<1, 1024, 0, stream>>>(deg, off, N);

    // ---- merged: scatter + (x -> packed + layer-0 dots) ----
    scatter_split_kernel<<<egrid + g8, 256, 0, stream>>>(esrc, edst, off, cursor, csrc, E, egrid,
                                                         x, vsd0, act_hi, act_lo, as_a, ad_a, N);
    amax_kernel<<<32, 256, 0, stream>>>(as_a, amax + 0, N);

    // ---- layer 0 ----
    gemm_mfma_kernel<<<gmp * 4, 256, 0, stream>>>(act_hi, act_lo, B0h, B0l, h, 256, lin, lb0, gm, N, 512);
    agg01_kernel<<<g8, 256, 0, stream>>>(h, as_a, ad_a, amax + 0, off, csrc, lin, b0,
                                         act_hi, act_lo, vsd1, as_b, ad_b, N);
    amax_kernel<<<32, 256, 0, stream>>>(as_b, amax + 4, N);

    // ---- layer 1 ----
    gemm_mfma_kernel<<<gmp * 4, 256, 0, stream>>>(act_hi, act_lo, B1h, B1l, h, 256, lin, lb1, gm, N, 512);
    agg01_kernel<<<g8, 256, 0, stream>>>(h, as_b, ad_b, amax + 4, off, csrc, lin, b1,
                                         act_hi, act_lo, vsd2, as_a, ad_a, N);
    amax_kernel<<<32, 256, 0, stream>>>(as_a, amax + 8, N);

    // ---- layer 2 ----
    gemm_mfma_kernel<<<gmp * 5, 256, 0, stream>>>(act_hi, act_lo, B2h, B2l, h, 512, lin, lb2, gm, N, 640);
    agg2_kernel<<<g4, 256, 0, stream>>>(h, as_a, ad_a, amax + 8, off, csrc, lin, b2, out, N);
}